// Round 1
// baseline (5859.970 us; speedup 1.0000x reference)
//
#include <hip/hip_runtime.h>
#include <math.h>

#define NB 4
#define NN 6000
#define NC 91
#define NG 32
#define NK 100

__device__ __constant__ float F_IMG = 800.0f;
#define SCORE_TH 0.05f
#define NMS_TH 0.5f
#define MATCH_TH 0.5f
#define MIN_SIZE 0.01f
#define BBOX_CLIP 4.135166556742356f  /* log(1000/16) */

// ---------------- init: zero per-image compaction counters ----------------
__global__ void init_kernel(int* counters) {
    int t = threadIdx.x;
    if (t < NB) counters[t] = 0;
}

// ---------------- matcher: IoU(gt, proposals), argmax over G --------------
__global__ void matcher_kernel(const float* __restrict__ props,
                               const float* __restrict__ gtb,
                               const int*  __restrict__ gtl,
                               float* __restrict__ out_assigned,
                               float* __restrict__ out_matched) {
    int t = blockIdx.x * blockDim.x + threadIdx.x;
    if (t >= NB * NN) return;
    int b = t / NN;
    const float* p = props + (size_t)t * 4;
    float px1 = p[0], py1 = p[1], px2 = p[2], py2 = p[3];
    float parea = __fmul_rn(__fsub_rn(px2, px1), __fsub_rn(py2, py1));
    float best = -1.0f; int bi = -1;
    for (int g = 0; g < NG; ++g) {
        const float* q = gtb + ((size_t)b * NG + g) * 4;
        float gx1 = q[0], gy1 = q[1], gx2 = q[2], gy2 = q[3];
        float garea = __fmul_rn(__fsub_rn(gx2, gx1), __fsub_rn(gy2, gy1));
        float ltx = fmaxf(gx1, px1), lty = fmaxf(gy1, py1);
        float rbx = fminf(gx2, px2), rby = fminf(gy2, py2);
        float wx = fmaxf(__fsub_rn(rbx, ltx), 0.0f);
        float wy = fmaxf(__fsub_rn(rby, lty), 0.0f);
        float inter = __fmul_rn(wx, wy);
        float iou = __fdiv_rn(inter, __fsub_rn(__fadd_rn(garea, parea), inter));
        if (iou > best) { best = iou; bi = g; }
    }
    int matched = (best >= MATCH_TH) ? bi : -1;
    int assigned = (matched >= 0) ? gtl[b * NG + matched] : 0;
    out_matched[t]  = (float)matched;
    out_assigned[t] = (float)assigned;
}

// ---------------- softmax row stats: one wave per row of 91 ---------------
__global__ void rowstats_kernel(const float* __restrict__ logits,
                                float* __restrict__ rowmax,
                                float* __restrict__ rowsum) {
    int gw = (blockIdx.x * blockDim.x + threadIdx.x) >> 6;
    int lane = threadIdx.x & 63;
    if (gw >= NB * NN) return;
    const float* row = logits + (size_t)gw * NC;
    float m = -INFINITY;
    for (int c = lane; c < NC; c += 64) m = fmaxf(m, row[c]);
    for (int o = 32; o; o >>= 1) m = fmaxf(m, __shfl_down(m, o));
    m = __shfl(m, 0);
    float s = 0.0f;
    for (int c = lane; c < NC; c += 64) s = __fadd_rn(s, expf(__fsub_rn(row[c], m)));
    for (int o = 32; o; o >>= 1) s = __fadd_rn(s, __shfl_down(s, o));
    if (lane == 0) { rowmax[gw] = m; rowsum[gw] = s; }
}

// -------- score + decode + validity filter -> compact entry append --------
// entry (8 floats, 32B): score, x1, y1, x2, y2, label, orig_flat_idx, pad
__global__ void compact_kernel(const float* __restrict__ logits,
                               const float* __restrict__ reg,
                               const float* __restrict__ props,
                               const float* __restrict__ rowmax,
                               const float* __restrict__ rowsum,
                               int* __restrict__ counters,
                               float* __restrict__ entries, int cap) {
    const int PER = NN * (NC - 1);
    int t = blockIdx.x * blockDim.x + threadIdx.x;
    if (t >= NB * PER) return;
    int b = t / PER, r = t % PER;
    int n = r / (NC - 1), c = r % (NC - 1) + 1;
    int row = b * NN + n;

    float l = logits[(size_t)row * NC + c];
    float score = __fdiv_rn(expf(__fsub_rn(l, rowmax[row])), rowsum[row]);

    const float* p = props + (size_t)row * 4;
    float w  = __fsub_rn(p[2], p[0]);
    float h  = __fsub_rn(p[3], p[1]);
    float cx = __fadd_rn(p[0], __fmul_rn(0.5f, w));
    float cy = __fadd_rn(p[1], __fmul_rn(0.5f, h));

    const float* rr = reg + (size_t)row * (NC * 4) + (size_t)c * 4;
    float dx = __fdiv_rn(rr[0], 10.0f);
    float dy = __fdiv_rn(rr[1], 10.0f);
    float dw = fminf(__fdiv_rn(rr[2], 5.0f), BBOX_CLIP);
    float dh = fminf(__fdiv_rn(rr[3], 5.0f), BBOX_CLIP);

    float pcx = __fadd_rn(__fmul_rn(dx, w), cx);
    float pcy = __fadd_rn(__fmul_rn(dy, h), cy);
    float pw  = __fmul_rn(expf(dw), w);
    float ph  = __fmul_rn(expf(dh), h);

    float x1 = __fsub_rn(pcx, __fmul_rn(0.5f, pw));
    float y1 = __fsub_rn(pcy, __fmul_rn(0.5f, ph));
    float x2 = __fadd_rn(pcx, __fmul_rn(0.5f, pw));
    float y2 = __fadd_rn(pcy, __fmul_rn(0.5f, ph));
    x1 = fminf(fmaxf(x1, 0.0f), 800.0f);
    y1 = fminf(fmaxf(y1, 0.0f), 800.0f);
    x2 = fminf(fmaxf(x2, 0.0f), 800.0f);
    y2 = fminf(fmaxf(y2, 0.0f), 800.0f);

    float ws_ = __fsub_rn(x2, x1);
    float hs_ = __fsub_rn(y2, y1);
    bool valid = (score > SCORE_TH) && (ws_ >= MIN_SIZE) && (hs_ >= MIN_SIZE);
    if (valid) {
        int idx = atomicAdd(&counters[b], 1);
        if (idx < cap) {
            float* e = entries + ((size_t)b * cap + idx) * 8;
            e[0] = score; e[1] = x1; e[2] = y1; e[3] = x2; e[4] = y2;
            e[5] = (float)c; e[6] = (float)r; e[7] = 0.0f;
        }
    }
}

// -------- greedy NMS: one block per image, K sequential argmax+suppress ----
__global__ __launch_bounds__(1024) void nms_kernel(const int* __restrict__ counters,
                                                   float* __restrict__ entries, int cap,
                                                   float* __restrict__ out_dets,
                                                   float* __restrict__ out_kl) {
    int b = blockIdx.x;
    int M = counters[b]; if (M > cap) M = cap;
    float* E = entries + (size_t)b * cap * 8;

    __shared__ float s_val[16];
    __shared__ int   s_idx[16];
    __shared__ float s_oi[16];
    __shared__ float sel[8];

    int tid = threadIdx.x, lane = tid & 63, wid = tid >> 6;

    for (int k = 0; k < NK; ++k) {
        // ---- argmax (value desc, tie -> smallest original flat index) ----
        float bv = -INFINITY; int bidx = -1; float boi = INFINITY;
        for (int i = tid; i < M; i += 1024) {
            float v  = E[(size_t)i * 8 + 0];
            float oi = E[(size_t)i * 8 + 6];
            if (v > bv || (v == bv && oi < boi)) { bv = v; bidx = i; boi = oi; }
        }
        for (int o = 32; o; o >>= 1) {
            float v2 = __shfl_down(bv, o);
            int   i2 = __shfl_down(bidx, o);
            float o2 = __shfl_down(boi, o);
            if (v2 > bv || (v2 == bv && o2 < boi)) { bv = v2; bidx = i2; boi = o2; }
        }
        if (lane == 0) { s_val[wid] = bv; s_idx[wid] = bidx; s_oi[wid] = boi; }
        __syncthreads();
        if (wid == 0) {
            float v  = (lane < 16) ? s_val[lane] : -INFINITY;
            int   ix = (lane < 16) ? s_idx[lane] : -1;
            float oi = (lane < 16) ? s_oi[lane] : INFINITY;
            for (int o = 8; o; o >>= 1) {
                float v2 = __shfl_down(v, o);
                int   i2 = __shfl_down(ix, o);
                float o2 = __shfl_down(oi, o);
                if (v2 > v || (v2 == v && o2 < oi)) { v = v2; ix = i2; oi = o2; }
            }
            if (lane == 0) {
                if (ix < 0 || v == -INFINITY) {
                    sel[0] = -INFINITY;
                } else {
                    for (int j = 0; j < 8; ++j) sel[j] = E[(size_t)ix * 8 + j];
                }
            }
        }
        __syncthreads();

        float selscore = sel[0];
        if (selscore == -INFINITY) {
            // no finite candidates remain: zero-fill remaining slots
            for (int kk = k; kk < NK; ++kk) {
                if (tid < 5) out_dets[((size_t)b * NK + kk) * 5 + tid] = 0.0f;
                if (tid == 5) out_kl[(size_t)b * NK + kk] = -1.0f;
            }
            break;
        }

        if (tid == 0) {
            size_t o = ((size_t)b * NK + k) * 5;
            out_dets[o + 0] = sel[1];
            out_dets[o + 1] = sel[2];
            out_dets[o + 2] = sel[3];
            out_dets[o + 3] = sel[4];
            out_dets[o + 4] = sel[0];
            out_kl[(size_t)b * NK + k] = sel[5];
        }

        // ---- suppress: IoU of offset boxes vs selected ----
        float tb  = __fmul_rn(sel[5], 801.0f);
        float bx1 = __fadd_rn(sel[1], tb), by1 = __fadd_rn(sel[2], tb);
        float bx2 = __fadd_rn(sel[3], tb), by2 = __fadd_rn(sel[4], tb);
        float barea = __fmul_rn(__fsub_rn(bx2, bx1), __fsub_rn(by2, by1));
        for (int i = tid; i < M; i += 1024) {
            float v = E[(size_t)i * 8 + 0];
            if (v == -INFINITY) continue;
            float lab = E[(size_t)i * 8 + 5];
            float t2  = __fmul_rn(lab, 801.0f);
            float ox1 = __fadd_rn(E[(size_t)i * 8 + 1], t2);
            float oy1 = __fadd_rn(E[(size_t)i * 8 + 2], t2);
            float ox2 = __fadd_rn(E[(size_t)i * 8 + 3], t2);
            float oy2 = __fadd_rn(E[(size_t)i * 8 + 4], t2);
            float oarea = __fmul_rn(__fsub_rn(ox2, ox1), __fsub_rn(oy2, oy1));
            float ltx = fmaxf(ox1, bx1), lty = fmaxf(oy1, by1);
            float rbx = fminf(ox2, bx2), rby = fminf(oy2, by2);
            float wx = fmaxf(__fsub_rn(rbx, ltx), 0.0f);
            float wy = fmaxf(__fsub_rn(rby, lty), 0.0f);
            float inter = __fmul_rn(wx, wy);
            float iou = __fdiv_rn(inter, __fsub_rn(__fadd_rn(oarea, barea), inter));
            if (iou > NMS_TH) E[(size_t)i * 8 + 0] = -INFINITY;
        }
        __syncthreads();
    }
}

extern "C" void kernel_launch(void* const* d_in, const int* in_sizes, int n_in,
                              void* d_out, int out_size, void* d_ws, size_t ws_size,
                              hipStream_t stream) {
    const float* logits = (const float*)d_in[0];
    const float* reg    = (const float*)d_in[1];
    const float* props  = (const float*)d_in[2];
    const float* gtb    = (const float*)d_in[3];
    const int*   gtl    = (const int*)d_in[4];

    float* out          = (float*)d_out;
    float* out_dets     = out;                              // NB*NK*5 = 2000
    float* out_kl       = out + NB * NK * 5;                // NB*NK   = 400
    float* out_assigned = out_kl + NB * NK;                 // NB*NN   = 24000
    float* out_matched  = out_assigned + NB * NN;           // NB*NN   = 24000

    char* ws = (char*)d_ws;
    int*   counters = (int*)ws;                             // 16 B used
    float* rowmax   = (float*)(ws + 1024);                  // 96000 B
    float* rowsum   = (float*)(ws + 1024 + (size_t)NB * NN * 4);
    size_t entOff   = 1024 + (size_t)NB * NN * 8;           // 193024
    float* entries  = (float*)(ws + entOff);
    long avail = (long)ws_size - (long)entOff;
    long capl  = (avail > 0) ? avail / ((long)NB * 32) : 0;
    long capmax = (long)NN * (NC - 1);
    int cap = (int)((capl > capmax) ? capmax : (capl < 0 ? 0 : capl));

    init_kernel<<<1, 64, 0, stream>>>(counters);
    matcher_kernel<<<(NB * NN + 255) / 256, 256, 0, stream>>>(
        props, gtb, gtl, out_assigned, out_matched);
    rowstats_kernel<<<(NB * NN * 64 + 255) / 256, 256, 0, stream>>>(
        logits, rowmax, rowsum);
    compact_kernel<<<(NB * NN * (NC - 1) + 255) / 256, 256, 0, stream>>>(
        logits, reg, props, rowmax, rowsum, counters, entries, cap);
    nms_kernel<<<NB, 1024, 0, stream>>>(counters, entries, cap, out_dets, out_kl);
}

// Round 2
// 628.744 us; speedup vs baseline: 9.3201x; 9.3201x over previous
//
#include <hip/hip_runtime.h>
#include <math.h>

#define NB 4
#define NN 6000
#define NC 91
#define NG 32
#define NK 100
#define NCLS (NC - 1)        /* 90 */
#define NBUC (NB * NCLS)     /* 360 */

#define SCORE_TH 0.05f
#define NMS_TH 0.5f
#define MATCH_TH 0.5f
#define MIN_SIZE 0.01f
#define BBOX_CLIP 4.135166556742356f  /* log(1000/16) */

// ---------------- init: zero per-bucket counters ----------------
__global__ void init_kernel(int* counts) {
    int t = blockIdx.x * blockDim.x + threadIdx.x;
    if (t < NBUC) counts[t] = 0;
}

// ---------------- matcher: IoU(gt, proposals), argmax over G --------------
__global__ void matcher_kernel(const float* __restrict__ props,
                               const float* __restrict__ gtb,
                               const int*  __restrict__ gtl,
                               float* __restrict__ out_assigned,
                               float* __restrict__ out_matched) {
    int t = blockIdx.x * blockDim.x + threadIdx.x;
    if (t >= NB * NN) return;
    int b = t / NN;
    const float4 p = *reinterpret_cast<const float4*>(props + (size_t)t * 4);
    float parea = __fmul_rn(__fsub_rn(p.z, p.x), __fsub_rn(p.w, p.y));
    float best = -1.0f; int bi = -1;
    for (int g = 0; g < NG; ++g) {
        const float4 q = *reinterpret_cast<const float4*>(gtb + ((size_t)b * NG + g) * 4);
        float garea = __fmul_rn(__fsub_rn(q.z, q.x), __fsub_rn(q.w, q.y));
        float ltx = fmaxf(q.x, p.x), lty = fmaxf(q.y, p.y);
        float rbx = fminf(q.z, p.z), rby = fminf(q.w, p.w);
        float wx = fmaxf(__fsub_rn(rbx, ltx), 0.0f);
        float wy = fmaxf(__fsub_rn(rby, lty), 0.0f);
        float inter = __fmul_rn(wx, wy);
        float iou = __fdiv_rn(inter, __fsub_rn(__fadd_rn(garea, parea), inter));
        if (iou > best) { best = iou; bi = g; }
    }
    int matched = (best >= MATCH_TH) ? bi : -1;
    int assigned = (matched >= 0) ? gtl[b * NG + matched] : 0;
    out_matched[t]  = (float)matched;
    out_assigned[t] = (float)assigned;
}

// ---------------- softmax row stats: one wave per row of 91 ---------------
__global__ void rowstats_kernel(const float* __restrict__ logits,
                                float* __restrict__ rowmax,
                                float* __restrict__ rowsum) {
    int gw = (blockIdx.x * blockDim.x + threadIdx.x) >> 6;
    int lane = threadIdx.x & 63;
    if (gw >= NB * NN) return;
    const float* row = logits + (size_t)gw * NC;
    float m = -INFINITY;
    for (int c = lane; c < NC; c += 64) m = fmaxf(m, row[c]);
    for (int o = 32; o; o >>= 1) m = fmaxf(m, __shfl_down(m, o));
    m = __shfl(m, 0);
    float s = 0.0f;
    for (int c = lane; c < NC; c += 64) s = __fadd_rn(s, expf(__fsub_rn(row[c], m)));
    for (int o = 32; o; o >>= 1) s = __fadd_rn(s, __shfl_down(s, o));
    if (lane == 0) { rowmax[gw] = m; rowsum[gw] = s; }
}

// ---------------- shared decode (must be identical in count & fill) --------
__device__ __forceinline__ bool decode_one(
    const float* __restrict__ logits, const float* __restrict__ reg,
    const float* __restrict__ props, const float* __restrict__ rowmax,
    const float* __restrict__ rowsum, int row, int c, float out[5])
{
    float l = logits[(size_t)row * NC + c];
    float score = __fdiv_rn(expf(__fsub_rn(l, rowmax[row])), rowsum[row]);

    const float4 p = *reinterpret_cast<const float4*>(props + (size_t)row * 4);
    float w  = __fsub_rn(p.z, p.x);
    float h  = __fsub_rn(p.w, p.y);
    float cx = __fadd_rn(p.x, __fmul_rn(0.5f, w));
    float cy = __fadd_rn(p.y, __fmul_rn(0.5f, h));

    const float4 r4 = *reinterpret_cast<const float4*>(
        reg + (size_t)row * (NC * 4) + (size_t)c * 4);
    float dx = __fdiv_rn(r4.x, 10.0f);
    float dy = __fdiv_rn(r4.y, 10.0f);
    float dw = fminf(__fdiv_rn(r4.z, 5.0f), BBOX_CLIP);
    float dh = fminf(__fdiv_rn(r4.w, 5.0f), BBOX_CLIP);

    float pcx = __fadd_rn(__fmul_rn(dx, w), cx);
    float pcy = __fadd_rn(__fmul_rn(dy, h), cy);
    float pw  = __fmul_rn(expf(dw), w);
    float ph  = __fmul_rn(expf(dh), h);

    float x1 = __fsub_rn(pcx, __fmul_rn(0.5f, pw));
    float y1 = __fsub_rn(pcy, __fmul_rn(0.5f, ph));
    float x2 = __fadd_rn(pcx, __fmul_rn(0.5f, pw));
    float y2 = __fadd_rn(pcy, __fmul_rn(0.5f, ph));
    x1 = fminf(fmaxf(x1, 0.0f), 800.0f);
    y1 = fminf(fmaxf(y1, 0.0f), 800.0f);
    x2 = fminf(fmaxf(x2, 0.0f), 800.0f);
    y2 = fminf(fmaxf(y2, 0.0f), 800.0f);

    out[0] = score; out[1] = x1; out[2] = y1; out[3] = x2; out[4] = y2;
    float ws_ = __fsub_rn(x2, x1);
    float hs_ = __fsub_rn(y2, y1);
    return (score > SCORE_TH) && (ws_ >= MIN_SIZE) && (hs_ >= MIN_SIZE);
}

// ---------------- pass 1: count valid per (image,class) bucket -------------
__global__ void count_kernel(const float* __restrict__ logits,
                             const float* __restrict__ reg,
                             const float* __restrict__ props,
                             const float* __restrict__ rowmax,
                             const float* __restrict__ rowsum,
                             int* __restrict__ counts) {
    const int PER = NN * NCLS;
    int t = blockIdx.x * blockDim.x + threadIdx.x;
    if (t >= NB * PER) return;
    int b = t / PER, r = t % PER;
    int n = r / NCLS, c = r % NCLS + 1;
    int row = b * NN + n;
    float o[5];
    if (decode_one(logits, reg, props, rowmax, rowsum, row, c, o))
        atomicAdd(&counts[b * NCLS + (c - 1)], 1);
}

// ---------------- exclusive scan of 360 counts (single block) --------------
__global__ __launch_bounds__(512) void scan_kernel(const int* __restrict__ counts,
                                                   int* __restrict__ offsets,
                                                   int* __restrict__ cursors) {
    __shared__ int sh[512];
    int tid = threadIdx.x;
    sh[tid] = (tid < NBUC) ? counts[tid] : 0;
    for (int off = 1; off < 512; off <<= 1) {
        __syncthreads();
        int x = (tid >= off) ? sh[tid - off] : 0;
        __syncthreads();
        sh[tid] += x;
    }
    __syncthreads();
    if (tid == 0) offsets[0] = 0;
    if (tid < NBUC) { offsets[tid + 1] = sh[tid]; cursors[tid] = 0; }
}

// ---------------- pass 2: fill entries bucket-contiguously ------------------
// entry (8 floats): score, x1, y1, x2, y2, label, orig_flat_idx, pad
__global__ void fill_kernel(const float* __restrict__ logits,
                            const float* __restrict__ reg,
                            const float* __restrict__ props,
                            const float* __restrict__ rowmax,
                            const float* __restrict__ rowsum,
                            const int* __restrict__ offsets,
                            int* __restrict__ cursors,
                            float* __restrict__ entries, int cap) {
    const int PER = NN * NCLS;
    int t = blockIdx.x * blockDim.x + threadIdx.x;
    if (t >= NB * PER) return;
    int b = t / PER, r = t % PER;
    int n = r / NCLS, c = r % NCLS + 1;
    int row = b * NN + n;
    float o[5];
    if (decode_one(logits, reg, props, rowmax, rowsum, row, c, o)) {
        int g = b * NCLS + (c - 1);
        int local = atomicAdd(&cursors[g], 1);
        int idx = offsets[g] + local;
        if (idx < cap) {
            float* e = entries + (size_t)idx * 8;
            e[0] = o[0]; e[1] = o[1]; e[2] = o[2]; e[3] = o[3]; e[4] = o[4];
            e[5] = (float)c; e[6] = (float)r; e[7] = 0.0f;
        }
    }
}

// -------- per-bucket greedy NMS: one block per (image,class) ----------------
__global__ __launch_bounds__(256) void bucket_nms_kernel(
    const int* __restrict__ offsets, int cap,
    float* __restrict__ entries,
    float* __restrict__ selbuf, int* __restrict__ selcnt) {
    int g = blockIdx.x;
    int off = offsets[g];
    int end = offsets[g + 1];
    if (off > cap) off = cap;
    if (end > cap) end = cap;
    int n = end - off;
    float* E = entries + (size_t)off * 8;

    __shared__ float s_val[4];
    __shared__ int   s_idx[4];
    __shared__ float s_oi[4];
    __shared__ float sel[8];

    int tid = threadIdx.x, lane = tid & 63, wid = tid >> 6;
    int kout = 0;

    for (int k = 0; k < NK; ++k) {
        // argmax over remaining (score desc, tie -> smallest flat idx)
        float bv = -INFINITY; int bidx = -1; float boi = INFINITY;
        for (int i = tid; i < n; i += 256) {
            float v  = E[(size_t)i * 8 + 0];
            float oi = E[(size_t)i * 8 + 6];
            if (v > bv || (v == bv && oi < boi)) { bv = v; bidx = i; boi = oi; }
        }
        for (int o = 32; o; o >>= 1) {
            float v2 = __shfl_down(bv, o);
            int   i2 = __shfl_down(bidx, o);
            float o2 = __shfl_down(boi, o);
            if (v2 > bv || (v2 == bv && o2 < boi)) { bv = v2; bidx = i2; boi = o2; }
        }
        if (lane == 0) { s_val[wid] = bv; s_idx[wid] = bidx; s_oi[wid] = boi; }
        __syncthreads();
        if (tid == 0) {
            float v = s_val[0]; int ix = s_idx[0]; float oi = s_oi[0];
            for (int wv = 1; wv < 4; ++wv)
                if (s_val[wv] > v || (s_val[wv] == v && s_oi[wv] < oi)) {
                    v = s_val[wv]; ix = s_idx[wv]; oi = s_oi[wv];
                }
            if (ix < 0 || v == -INFINITY) sel[0] = -INFINITY;
            else for (int j = 0; j < 8; ++j) sel[j] = E[(size_t)ix * 8 + j];
        }
        __syncthreads();
        if (sel[0] == -INFINITY) break;

        if (tid == 0) {
            float* so = selbuf + ((size_t)g * NK + k) * 8;
            for (int j = 0; j < 8; ++j) so[j] = sel[j];
        }

        // suppress within bucket using OFFSET coordinates (bit-exact w/ ref)
        float tb  = __fmul_rn(sel[5], 801.0f);
        float bx1 = __fadd_rn(sel[1], tb), by1 = __fadd_rn(sel[2], tb);
        float bx2 = __fadd_rn(sel[3], tb), by2 = __fadd_rn(sel[4], tb);
        float barea = __fmul_rn(__fsub_rn(bx2, bx1), __fsub_rn(by2, by1));
        for (int i = tid; i < n; i += 256) {
            float v = E[(size_t)i * 8 + 0];
            if (v == -INFINITY) continue;
            float ox1 = __fadd_rn(E[(size_t)i * 8 + 1], tb);
            float oy1 = __fadd_rn(E[(size_t)i * 8 + 2], tb);
            float ox2 = __fadd_rn(E[(size_t)i * 8 + 3], tb);
            float oy2 = __fadd_rn(E[(size_t)i * 8 + 4], tb);
            float oarea = __fmul_rn(__fsub_rn(ox2, ox1), __fsub_rn(oy2, oy1));
            float ltx = fmaxf(ox1, bx1), lty = fmaxf(oy1, by1);
            float rbx = fminf(ox2, bx2), rby = fminf(oy2, by2);
            float wx = fmaxf(__fsub_rn(rbx, ltx), 0.0f);
            float wy = fmaxf(__fsub_rn(rby, lty), 0.0f);
            float inter = __fmul_rn(wx, wy);
            float iou = __fdiv_rn(inter, __fsub_rn(__fadd_rn(oarea, barea), inter));
            if (iou > NMS_TH) E[(size_t)i * 8 + 0] = -INFINITY;
        }
        kout = k + 1;
        __syncthreads();
    }
    if (tid == 0) selcnt[g] = kout;
}

// -------- merge: per image, pick top-K across 90 sorted bucket lists --------
__global__ __launch_bounds__(64) void merge_kernel(
    const float* __restrict__ selbuf, const int* __restrict__ selcnt,
    float* __restrict__ out_dets, float* __restrict__ out_kl) {
    int b = blockIdx.x;
    int lane = threadIdx.x;

    int g0 = b * NCLS + lane;                               // slots 0..63
    int g1 = (lane < NCLS - 64) ? (b * NCLS + 64 + lane) : -1;  // slots 64..89
    int c0 = selcnt[g0], p0 = 0;
    float sc0 = -INFINITY, oi0 = INFINITY;
    if (p0 < c0) {
        const float* h = selbuf + ((size_t)g0 * NK + p0) * 8;
        sc0 = h[0]; oi0 = h[6];
    }
    int c1 = 0, p1 = 0;
    float sc1 = -INFINITY, oi1 = INFINITY;
    if (g1 >= 0) {
        c1 = selcnt[g1];
        if (p1 < c1) {
            const float* h = selbuf + ((size_t)g1 * NK + p1) * 8;
            sc1 = h[0]; oi1 = h[6];
        }
    }

    for (int k = 0; k < NK; ++k) {
        float bsc, boi; int bslot;
        if (sc1 > sc0 || (sc1 == sc0 && oi1 < oi0)) { bsc = sc1; boi = oi1; bslot = lane + 64; }
        else                                         { bsc = sc0; boi = oi0; bslot = lane; }
        for (int o = 32; o; o >>= 1) {
            float s2 = __shfl_down(bsc, o);
            float o2 = __shfl_down(boi, o);
            int   g2 = __shfl_down(bslot, o);
            if (s2 > bsc || (s2 == bsc && o2 < boi)) { bsc = s2; boi = o2; bslot = g2; }
        }
        bsc   = __shfl(bsc, 0);
        bslot = __shfl(bslot, 0);

        if (bsc == -INFINITY) {
            for (int kk = k; kk < NK; ++kk) {
                if (lane < 5)  out_dets[((size_t)b * NK + kk) * 5 + lane] = 0.0f;
                if (lane == 5) out_kl[(size_t)b * NK + kk] = -1.0f;
            }
            return;
        }

        int owner = bslot & 63;
        if (lane == owner) {
            const float* e;
            if (bslot < 64) e = selbuf + ((size_t)g0 * NK + p0) * 8;
            else            e = selbuf + ((size_t)g1 * NK + p1) * 8;
            size_t o = ((size_t)b * NK + k) * 5;
            out_dets[o + 0] = e[1];
            out_dets[o + 1] = e[2];
            out_dets[o + 2] = e[3];
            out_dets[o + 3] = e[4];
            out_dets[o + 4] = e[0];
            out_kl[(size_t)b * NK + k] = e[5];
            if (bslot < 64) {
                p0++;
                if (p0 < c0) { const float* h = selbuf + ((size_t)g0 * NK + p0) * 8; sc0 = h[0]; oi0 = h[6]; }
                else         { sc0 = -INFINITY; oi0 = INFINITY; }
            } else {
                p1++;
                if (p1 < c1) { const float* h = selbuf + ((size_t)g1 * NK + p1) * 8; sc1 = h[0]; oi1 = h[6]; }
                else         { sc1 = -INFINITY; oi1 = INFINITY; }
            }
        }
    }
}

extern "C" void kernel_launch(void* const* d_in, const int* in_sizes, int n_in,
                              void* d_out, int out_size, void* d_ws, size_t ws_size,
                              hipStream_t stream) {
    const float* logits = (const float*)d_in[0];
    const float* reg    = (const float*)d_in[1];
    const float* props  = (const float*)d_in[2];
    const float* gtb    = (const float*)d_in[3];
    const int*   gtl    = (const int*)d_in[4];

    float* out          = (float*)d_out;
    float* out_dets     = out;                    // NB*NK*5 = 2000
    float* out_kl       = out + NB * NK * 5;      // NB*NK   = 400
    float* out_assigned = out_kl + NB * NK;       // NB*NN   = 24000
    float* out_matched  = out_assigned + NB * NN; // NB*NN   = 24000

    char* ws = (char*)d_ws;
    int*   counts  = (int*)(ws + 0);              // 1440 B
    int*   cursors = (int*)(ws + 2048);           // 1440 B
    int*   offsets = (int*)(ws + 4096);           // 1444 B
    int*   selcnt  = (int*)(ws + 8192);           // 1440 B
    float* rowmax  = (float*)(ws + 16384);        // 96000 B
    float* rowsum  = (float*)(ws + 112384);       // 96000 B
    float* selbuf  = (float*)(ws + 212992);       // 360*100*32 = 1152000 B
    size_t entOff  = 1368064;
    float* entries = (float*)(ws + entOff);
    long avail = (long)ws_size - (long)entOff;
    long capl  = (avail > 0) ? avail / 32 : 0;
    long capmax = (long)NB * NN * NCLS;
    int cap = (int)((capl > capmax) ? capmax : (capl < 0 ? 0 : capl));

    const int TOT = NB * NN * NCLS;

    init_kernel<<<1, 512, 0, stream>>>(counts);
    matcher_kernel<<<(NB * NN + 255) / 256, 256, 0, stream>>>(
        props, gtb, gtl, out_assigned, out_matched);
    rowstats_kernel<<<(NB * NN * 64 + 255) / 256, 256, 0, stream>>>(
        logits, rowmax, rowsum);
    count_kernel<<<(TOT + 255) / 256, 256, 0, stream>>>(
        logits, reg, props, rowmax, rowsum, counts);
    scan_kernel<<<1, 512, 0, stream>>>(counts, offsets, cursors);
    fill_kernel<<<(TOT + 255) / 256, 256, 0, stream>>>(
        logits, reg, props, rowmax, rowsum, offsets, cursors, entries, cap);
    bucket_nms_kernel<<<NBUC, 256, 0, stream>>>(
        offsets, cap, entries, selbuf, selcnt);
    merge_kernel<<<NB, 64, 0, stream>>>(selbuf, selcnt, out_dets, out_kl);
}

// Round 3
// 395.270 us; speedup vs baseline: 14.8252x; 1.5907x over previous
//
#include <hip/hip_runtime.h>
#include <math.h>

#define NB 4
#define NN 6000
#define NC 91
#define NG 32
#define NK 100
#define NCLS (NC - 1)        /* 90 */
#define NBUC (NB * NCLS)     /* 360 */
#define SLOTS_MAX 2048

#define SCORE_TH 0.05f
#define NMS_TH 0.5f
#define MATCH_TH 0.5f
#define MIN_SIZE 0.01f
#define BBOX_CLIP 4.135166556742356f  /* log(1000/16) */
/* fdiv_rn(inter,den) > 0.5f  <=>  (double)inter > C_SUP*(double)den  (exact) */
#define C_SUP 0.5000000298023223876953125

// ---------------- matcher (+ zero bucket cursors in block 0) ---------------
__global__ __launch_bounds__(512) void matcher_kernel(
    const float* __restrict__ props, const float* __restrict__ gtb,
    const int* __restrict__ gtl, float* __restrict__ out_assigned,
    float* __restrict__ out_matched, int* __restrict__ cursors) {
    if (blockIdx.x == 0 && threadIdx.x < NBUC) cursors[threadIdx.x] = 0;
    int t = blockIdx.x * blockDim.x + threadIdx.x;
    if (t >= NB * NN) return;
    int b = t / NN;
    const float4 p = *reinterpret_cast<const float4*>(props + (size_t)t * 4);
    float parea = __fmul_rn(__fsub_rn(p.z, p.x), __fsub_rn(p.w, p.y));
    float best = -1.0f; int bi = -1;
    for (int g = 0; g < NG; ++g) {
        const float4 q = *reinterpret_cast<const float4*>(gtb + ((size_t)b * NG + g) * 4);
        float garea = __fmul_rn(__fsub_rn(q.z, q.x), __fsub_rn(q.w, q.y));
        float ltx = fmaxf(q.x, p.x), lty = fmaxf(q.y, p.y);
        float rbx = fminf(q.z, p.z), rby = fminf(q.w, p.w);
        float wx = fmaxf(__fsub_rn(rbx, ltx), 0.0f);
        float wy = fmaxf(__fsub_rn(rby, lty), 0.0f);
        float inter = __fmul_rn(wx, wy);
        float iou = __fdiv_rn(inter, __fsub_rn(__fadd_rn(garea, parea), inter));
        if (iou > best) { best = iou; bi = g; }
    }
    int matched = (best >= MATCH_TH) ? bi : -1;
    int assigned = (matched >= 0) ? gtl[b * NG + matched] : 0;
    out_matched[t]  = (float)matched;
    out_assigned[t] = (float)assigned;
}

// ---------------- softmax row stats: one wave per row of 91 ---------------
__global__ void rowstats_kernel(const float* __restrict__ logits,
                                float* __restrict__ rowmax,
                                float* __restrict__ rowsum) {
    int gw = (blockIdx.x * blockDim.x + threadIdx.x) >> 6;
    int lane = threadIdx.x & 63;
    if (gw >= NB * NN) return;
    const float* row = logits + (size_t)gw * NC;
    float m = -INFINITY;
    for (int c = lane; c < NC; c += 64) m = fmaxf(m, row[c]);
    for (int o = 32; o; o >>= 1) m = fmaxf(m, __shfl_down(m, o));
    m = __shfl(m, 0);
    float s = 0.0f;
    for (int c = lane; c < NC; c += 64) s = __fadd_rn(s, expf(__fsub_rn(row[c], m)));
    for (int o = 32; o; o >>= 1) s = __fadd_rn(s, __shfl_down(s, o));
    if (lane == 0) { rowmax[gw] = m; rowsum[gw] = s; }
}

// ---------------- decode (identical math to rounds 1-2, absmax==0) ---------
__device__ __forceinline__ bool decode_one(
    const float* __restrict__ logits, const float* __restrict__ reg,
    const float* __restrict__ props, const float* __restrict__ rowmax,
    const float* __restrict__ rowsum, int row, int c, float out[5])
{
    float l = logits[(size_t)row * NC + c];
    float score = __fdiv_rn(expf(__fsub_rn(l, rowmax[row])), rowsum[row]);

    const float4 p = *reinterpret_cast<const float4*>(props + (size_t)row * 4);
    float w  = __fsub_rn(p.z, p.x);
    float h  = __fsub_rn(p.w, p.y);
    float cx = __fadd_rn(p.x, __fmul_rn(0.5f, w));
    float cy = __fadd_rn(p.y, __fmul_rn(0.5f, h));

    const float4 r4 = *reinterpret_cast<const float4*>(
        reg + (size_t)row * (NC * 4) + (size_t)c * 4);
    float dx = __fdiv_rn(r4.x, 10.0f);
    float dy = __fdiv_rn(r4.y, 10.0f);
    float dw = fminf(__fdiv_rn(r4.z, 5.0f), BBOX_CLIP);
    float dh = fminf(__fdiv_rn(r4.w, 5.0f), BBOX_CLIP);

    float pcx = __fadd_rn(__fmul_rn(dx, w), cx);
    float pcy = __fadd_rn(__fmul_rn(dy, h), cy);
    float pw  = __fmul_rn(expf(dw), w);
    float ph  = __fmul_rn(expf(dh), h);

    float x1 = __fsub_rn(pcx, __fmul_rn(0.5f, pw));
    float y1 = __fsub_rn(pcy, __fmul_rn(0.5f, ph));
    float x2 = __fadd_rn(pcx, __fmul_rn(0.5f, pw));
    float y2 = __fadd_rn(pcy, __fmul_rn(0.5f, ph));
    x1 = fminf(fmaxf(x1, 0.0f), 800.0f);
    y1 = fminf(fmaxf(y1, 0.0f), 800.0f);
    x2 = fminf(fmaxf(x2, 0.0f), 800.0f);
    y2 = fminf(fmaxf(y2, 0.0f), 800.0f);

    out[0] = score; out[1] = x1; out[2] = y1; out[3] = x2; out[4] = y2;
    float ws_ = __fsub_rn(x2, x1);
    float hs_ = __fsub_rn(y2, y1);
    return (score > SCORE_TH) && (ws_ >= MIN_SIZE) && (hs_ >= MIN_SIZE);
}

// ---------------- single-pass fill into per-bucket SoA slots ---------------
__global__ void fill_kernel(const float* __restrict__ logits,
                            const float* __restrict__ reg,
                            const float* __restrict__ props,
                            const float* __restrict__ rowmax,
                            const float* __restrict__ rowsum,
                            int* __restrict__ cursors,
                            float* __restrict__ e_sc, float* __restrict__ e_x1,
                            float* __restrict__ e_y1, float* __restrict__ e_x2,
                            float* __restrict__ e_y2, float* __restrict__ e_id,
                            int slots) {
    const int PER = NN * NCLS;
    int t = blockIdx.x * blockDim.x + threadIdx.x;
    if (t >= NB * PER) return;
    int b = t / PER, r = t % PER;
    int n = r / NCLS, c = r % NCLS + 1;
    int row = b * NN + n;
    float o[5];
    if (decode_one(logits, reg, props, rowmax, rowsum, row, c, o)) {
        int g = b * NCLS + (c - 1);
        int pos = atomicAdd(&cursors[g], 1);
        if (pos < slots) {
            size_t idx = (size_t)g * slots + pos;
            e_sc[idx] = o[0]; e_x1[idx] = o[1]; e_y1[idx] = o[2];
            e_x2[idx] = o[3]; e_y2[idx] = o[4]; e_id[idx] = (float)r;
        }
    }
}

// ---------------- register-resident wave NMS ------------------------------
template <int CAP>
__device__ __forceinline__ void nms_reg(
    int g, int n, const float* __restrict__ SC, const float* __restrict__ X1,
    const float* __restrict__ Y1, const float* __restrict__ X2,
    const float* __restrict__ Y2, const float* __restrict__ ID,
    float tb, float cls, float* __restrict__ selbuf, int* __restrict__ selcnt)
{
    int lane = threadIdx.x;
    float s[CAP], x1[CAP], y1[CAP], x2[CAP], y2[CAP], idv[CAP], ar[CAP];
#pragma unroll
    for (int j = 0; j < CAP; ++j) {
        int sl = lane + j * 64;
        bool v = sl < n;
        s[j]   = v ? SC[sl] : -INFINITY;
        x1[j]  = v ? X1[sl] : 0.0f;
        y1[j]  = v ? Y1[sl] : 0.0f;
        x2[j]  = v ? X2[sl] : 0.0f;
        y2[j]  = v ? Y2[sl] : 0.0f;
        idv[j] = v ? ID[sl] : INFINITY;
        float ox1 = __fadd_rn(x1[j], tb), oy1 = __fadd_rn(y1[j], tb);
        float ox2 = __fadd_rn(x2[j], tb), oy2 = __fadd_rn(y2[j], tb);
        ar[j] = __fmul_rn(__fsub_rn(ox2, ox1), __fsub_rn(oy2, oy1));
    }
    int kout = 0;
    for (int k = 0; k < NK; ++k) {
        // local argmax (score desc, idx asc)
        float bv = -INFINITY, boi = INFINITY; int bsl = 0;
#pragma unroll
        for (int j = 0; j < CAP; ++j) {
            bool bt = (s[j] > bv) || (s[j] == bv && idv[j] < boi);
            bv = bt ? s[j] : bv; boi = bt ? idv[j] : boi; bsl = bt ? j : bsl;
        }
        // butterfly reduce -> every lane holds global winner (bv, boi, wl)
        int wl = lane;
#pragma unroll
        for (int o = 1; o < 64; o <<= 1) {
            float v2 = __shfl_xor(bv, o); float o2 = __shfl_xor(boi, o);
            int l2 = __shfl_xor(wl, o);
            bool bt = (v2 > bv) || (v2 == bv && o2 < boi);
            bv = bt ? v2 : bv; boi = bt ? o2 : boi; wl = bt ? l2 : wl;
        }
        if (bv == -INFINITY) break;
        // each lane materializes its own local-best entry (static select chain)
        float cs = s[0], cx1 = x1[0], cy1 = y1[0], cx2 = x2[0], cy2 = y2[0];
        float cid = idv[0], car = ar[0];
#pragma unroll
        for (int j = 1; j < CAP; ++j) {
            bool pk = (bsl == j);
            cs = pk ? s[j] : cs; cx1 = pk ? x1[j] : cx1; cy1 = pk ? y1[j] : cy1;
            cx2 = pk ? x2[j] : cx2; cy2 = pk ? y2[j] : cy2;
            cid = pk ? idv[j] : cid; car = pk ? ar[j] : car;
        }
        float sx1 = __shfl(cx1, wl), sy1 = __shfl(cy1, wl);
        float sx2 = __shfl(cx2, wl), sy2 = __shfl(cy2, wl);
        float sar = __shfl(car, wl);
        if (lane == wl) {
            float* so = selbuf + ((size_t)g * NK + k) * 8;
            so[0] = cs; so[1] = cx1; so[2] = cy1; so[3] = cx2; so[4] = cy2;
            so[5] = cls; so[6] = cid; so[7] = 0.0f;
        }
        float bx1 = __fadd_rn(sx1, tb), by1 = __fadd_rn(sy1, tb);
        float bx2 = __fadd_rn(sx2, tb), by2 = __fadd_rn(sy2, tb);
#pragma unroll
        for (int j = 0; j < CAP; ++j) {
            float ox1 = __fadd_rn(x1[j], tb), oy1 = __fadd_rn(y1[j], tb);
            float ox2 = __fadd_rn(x2[j], tb), oy2 = __fadd_rn(y2[j], tb);
            float ltx = fmaxf(ox1, bx1), lty = fmaxf(oy1, by1);
            float rbx = fminf(ox2, bx2), rby = fminf(oy2, by2);
            float wx = fmaxf(__fsub_rn(rbx, ltx), 0.0f);
            float wy = fmaxf(__fsub_rn(rby, lty), 0.0f);
            float inter = __fmul_rn(wx, wy);
            float den = __fsub_rn(__fadd_rn(ar[j], sar), inter);
            bool sup = ((double)inter > C_SUP * (double)den);
            s[j] = sup ? -INFINITY : s[j];
        }
        kout = k + 1;
    }
    if (lane == 0) selcnt[g] = kout;
}

// fallback for n > 1024 (never expected on this data)
__device__ void nms_glb(int g, int n, float* __restrict__ SC,
                        const float* __restrict__ X1, const float* __restrict__ Y1,
                        const float* __restrict__ X2, const float* __restrict__ Y2,
                        const float* __restrict__ ID, float tb, float cls,
                        float* __restrict__ selbuf, int* __restrict__ selcnt)
{
    int lane = threadIdx.x;
    int kout = 0;
    for (int k = 0; k < NK; ++k) {
        float bv = -INFINITY, boi = INFINITY; int bi = -1;
        for (int i = lane; i < n; i += 64) {
            float v = SC[i], oi = ID[i];
            if (v > bv || (v == bv && oi < boi)) { bv = v; boi = oi; bi = i; }
        }
        int wl = lane;
        for (int o = 1; o < 64; o <<= 1) {
            float v2 = __shfl_xor(bv, o); float o2 = __shfl_xor(boi, o);
            int l2 = __shfl_xor(wl, o);
            bool bt = (v2 > bv) || (v2 == bv && o2 < boi);
            bv = bt ? v2 : bv; boi = bt ? o2 : boi; wl = bt ? l2 : wl;
        }
        if (bv == -INFINITY) break;
        int wi = __shfl(bi, wl);
        float sx1 = X1[wi], sy1 = Y1[wi], sx2 = X2[wi], sy2 = Y2[wi];
        if (lane == wl) {
            float* so = selbuf + ((size_t)g * NK + k) * 8;
            so[0] = bv; so[1] = sx1; so[2] = sy1; so[3] = sx2; so[4] = sy2;
            so[5] = cls; so[6] = boi; so[7] = 0.0f;
        }
        float bx1 = __fadd_rn(sx1, tb), by1 = __fadd_rn(sy1, tb);
        float bx2 = __fadd_rn(sx2, tb), by2 = __fadd_rn(sy2, tb);
        float sar = __fmul_rn(__fsub_rn(bx2, bx1), __fsub_rn(by2, by1));
        for (int i = lane; i < n; i += 64) {
            float v = SC[i];
            if (v == -INFINITY) continue;
            float ox1 = __fadd_rn(X1[i], tb), oy1 = __fadd_rn(Y1[i], tb);
            float ox2 = __fadd_rn(X2[i], tb), oy2 = __fadd_rn(Y2[i], tb);
            float oar = __fmul_rn(__fsub_rn(ox2, ox1), __fsub_rn(oy2, oy1));
            float ltx = fmaxf(ox1, bx1), lty = fmaxf(oy1, by1);
            float rbx = fminf(ox2, bx2), rby = fminf(oy2, by2);
            float wx = fmaxf(__fsub_rn(rbx, ltx), 0.0f);
            float wy = fmaxf(__fsub_rn(rby, lty), 0.0f);
            float inter = __fmul_rn(wx, wy);
            float den = __fsub_rn(__fadd_rn(oar, sar), inter);
            if ((double)inter > C_SUP * (double)den) SC[i] = -INFINITY;
        }
        kout = k + 1;
    }
    if (lane == 0) selcnt[g] = kout;
}

__global__ __launch_bounds__(64) void bucket_nms_kernel(
    const int* __restrict__ cursors, int slots,
    float* __restrict__ e_sc, const float* __restrict__ e_x1,
    const float* __restrict__ e_y1, const float* __restrict__ e_x2,
    const float* __restrict__ e_y2, const float* __restrict__ e_id,
    float* __restrict__ selbuf, int* __restrict__ selcnt)
{
    int g = blockIdx.x;
    int n = cursors[g]; if (n > slots) n = slots;
    size_t base = (size_t)g * slots;
    float cls = (float)(g % NCLS + 1);
    float tb = __fmul_rn(cls, 801.0f);
    if (n <= 512)
        nms_reg<8>(g, n, e_sc + base, e_x1 + base, e_y1 + base, e_x2 + base,
                   e_y2 + base, e_id + base, tb, cls, selbuf, selcnt);
    else if (n <= 1024)
        nms_reg<16>(g, n, e_sc + base, e_x1 + base, e_y1 + base, e_x2 + base,
                    e_y2 + base, e_id + base, tb, cls, selbuf, selcnt);
    else
        nms_glb(g, n, e_sc + base, e_x1 + base, e_y1 + base, e_x2 + base,
                e_y2 + base, e_id + base, tb, cls, selbuf, selcnt);
}

// ---------------- merge with head prefetch ---------------------------------
__device__ __forceinline__ void loadkey(const float* __restrict__ selbuf,
                                        int g, int p, int c, float& s, float& i) {
    if (p < c) {
        const float* h = selbuf + ((size_t)g * NK + p) * 8;
        s = h[0]; i = h[6];
    } else { s = -INFINITY; i = INFINITY; }
}

__global__ __launch_bounds__(64) void merge_kernel(
    const float* __restrict__ selbuf, const int* __restrict__ selcnt,
    float* __restrict__ out_dets, float* __restrict__ out_kl) {
    int b = blockIdx.x, lane = threadIdx.x;
    int g0 = b * NCLS + lane;
    int g1 = (lane < NCLS - 64) ? g0 + 64 : -1;
    int c0 = selcnt[g0];
    int c1 = (g1 >= 0) ? selcnt[g1] : 0;
    int p0 = 0, p1 = 0;
    float s0c, i0c, s0n, i0n, s1c, i1c, s1n, i1n;
    loadkey(selbuf, g0, 0, c0, s0c, i0c);
    loadkey(selbuf, g0, 1, c0, s0n, i0n);
    if (g1 >= 0) {
        loadkey(selbuf, g1, 0, c1, s1c, i1c);
        loadkey(selbuf, g1, 1, c1, s1n, i1n);
    } else { s1c = -INFINITY; i1c = INFINITY; s1n = -INFINITY; i1n = INFINITY; }

    for (int k = 0; k < NK; ++k) {
        bool t1 = (s1c > s0c) || (s1c == s0c && i1c < i0c);
        float bs = t1 ? s1c : s0c;
        float bi = t1 ? i1c : i0c;
        int bslot = t1 ? (lane + 64) : lane;
        for (int o = 1; o < 64; o <<= 1) {
            float s2 = __shfl_xor(bs, o); float x2 = __shfl_xor(bi, o);
            int b2 = __shfl_xor(bslot, o);
            bool bt = (s2 > bs) || (s2 == bs && x2 < bi);
            bs = bt ? s2 : bs; bi = bt ? x2 : bi; bslot = bt ? b2 : bslot;
        }
        if (bs == -INFINITY) {
            for (int z = k * 5 + lane; z < NK * 5; z += 64)
                out_dets[(size_t)b * NK * 5 + z] = 0.0f;
            for (int z = k + lane; z < NK; z += 64)
                out_kl[(size_t)b * NK + z] = -1.0f;
            return;
        }
        int owner = bslot & 63;
        if (lane == owner) {
            bool isA = (bslot < 64);
            int g = isA ? g0 : g1;
            int p = isA ? p0 : p1;
            const float* e = selbuf + ((size_t)g * NK + p) * 8;
            size_t o = ((size_t)b * NK + k) * 5;
            out_dets[o + 0] = e[1]; out_dets[o + 1] = e[2];
            out_dets[o + 2] = e[3]; out_dets[o + 3] = e[4];
            out_dets[o + 4] = e[0];
            out_kl[(size_t)b * NK + k] = e[5];
            if (isA) { p0++; s0c = s0n; i0c = i0n; loadkey(selbuf, g0, p0 + 1, c0, s0n, i0n); }
            else     { p1++; s1c = s1n; i1c = i1n; loadkey(selbuf, g1, p1 + 1, c1, s1n, i1n); }
        }
    }
}

extern "C" void kernel_launch(void* const* d_in, const int* in_sizes, int n_in,
                              void* d_out, int out_size, void* d_ws, size_t ws_size,
                              hipStream_t stream) {
    const float* logits = (const float*)d_in[0];
    const float* reg    = (const float*)d_in[1];
    const float* props  = (const float*)d_in[2];
    const float* gtb    = (const float*)d_in[3];
    const int*   gtl    = (const int*)d_in[4];

    float* out          = (float*)d_out;
    float* out_dets     = out;                    // NB*NK*5 = 2000
    float* out_kl       = out + NB * NK * 5;      // NB*NK   = 400
    float* out_assigned = out_kl + NB * NK;       // NB*NN   = 24000
    float* out_matched  = out_assigned + NB * NN; // NB*NN   = 24000

    char* ws = (char*)d_ws;
    int*   cursors = (int*)(ws + 0);              // 1440 B
    int*   selcnt  = (int*)(ws + 2048);           // 1440 B
    float* rowmax  = (float*)(ws + 4096);         // 96000 B
    float* rowsum  = (float*)(ws + 100352);       // 96000 B
    float* selbuf  = (float*)(ws + 196608);       // 360*100*8*4 = 1152000 B
    size_t off_ent = 1348608;

    long avail = (long)ws_size - (long)off_ent;
    long per_slot = 6L * 4L * NBUC;               // 8640 B per slot index
    long slotsl = (avail > 0) ? avail / per_slot : 0;
    int slots = (int)((slotsl > SLOTS_MAX) ? SLOTS_MAX : (slotsl < 0 ? 0 : slotsl));

    size_t fsz = (size_t)NBUC * slots;            // floats per field
    float* e_sc = (float*)(ws + off_ent);
    float* e_x1 = e_sc + fsz;
    float* e_y1 = e_x1 + fsz;
    float* e_x2 = e_y1 + fsz;
    float* e_y2 = e_x2 + fsz;
    float* e_id = e_y2 + fsz;

    const int TOT = NB * NN * NCLS;

    matcher_kernel<<<(NB * NN + 511) / 512, 512, 0, stream>>>(
        props, gtb, gtl, out_assigned, out_matched, cursors);
    rowstats_kernel<<<(NB * NN * 64 + 255) / 256, 256, 0, stream>>>(
        logits, rowmax, rowsum);
    fill_kernel<<<(TOT + 255) / 256, 256, 0, stream>>>(
        logits, reg, props, rowmax, rowsum, cursors,
        e_sc, e_x1, e_y1, e_x2, e_y2, e_id, slots);
    bucket_nms_kernel<<<NBUC, 64, 0, stream>>>(
        cursors, slots, e_sc, e_x1, e_y1, e_x2, e_y2, e_id, selbuf, selcnt);
    merge_kernel<<<NB, 64, 0, stream>>>(selbuf, selcnt, out_dets, out_kl);
}

// Round 4
// 256.146 us; speedup vs baseline: 22.8774x; 1.5431x over previous
//
#include <hip/hip_runtime.h>
#include <math.h>

#define NB 4
#define NN 6000
#define NC 91
#define NG 32
#define NK 100
#define NCLS (NC - 1)        /* 90 */
#define NBUC (NB * NCLS)     /* 360 */
#define SLOTS_MAX 2048
#define CUR_STRIDE 32        /* one cursor per 128B line (atomic padding) */

#define SCORE_TH 0.05f
#define NMS_TH 0.5f
#define MATCH_TH 0.5f
#define MIN_SIZE 0.01f
#define BBOX_CLIP 4.135166556742356f  /* log(1000/16) */
/* fdiv_rn(inter,den) > 0.5f  <=>  (double)inter > C_SUP*(double)den  (exact) */
#define C_SUP 0.5000000298023223876953125

// ------- matcher (+ zero padded bucket cursors using the whole grid) -------
__global__ __launch_bounds__(512) void matcher_kernel(
    const float* __restrict__ props, const float* __restrict__ gtb,
    const int* __restrict__ gtl, float* __restrict__ out_assigned,
    float* __restrict__ out_matched, int* __restrict__ cursors) {
    int t = blockIdx.x * blockDim.x + threadIdx.x;
    if (t < NBUC * CUR_STRIDE) cursors[t] = 0;
    if (t >= NB * NN) return;
    int b = t / NN;
    const float4 p = *reinterpret_cast<const float4*>(props + (size_t)t * 4);
    float parea = __fmul_rn(__fsub_rn(p.z, p.x), __fsub_rn(p.w, p.y));
    float best = -1.0f; int bi = -1;
    for (int g = 0; g < NG; ++g) {
        const float4 q = *reinterpret_cast<const float4*>(gtb + ((size_t)b * NG + g) * 4);
        float garea = __fmul_rn(__fsub_rn(q.z, q.x), __fsub_rn(q.w, q.y));
        float ltx = fmaxf(q.x, p.x), lty = fmaxf(q.y, p.y);
        float rbx = fminf(q.z, p.z), rby = fminf(q.w, p.w);
        float wx = fmaxf(__fsub_rn(rbx, ltx), 0.0f);
        float wy = fmaxf(__fsub_rn(rby, lty), 0.0f);
        float inter = __fmul_rn(wx, wy);
        float iou = __fdiv_rn(inter, __fsub_rn(__fadd_rn(garea, parea), inter));
        if (iou > best) { best = iou; bi = g; }
    }
    int matched = (best >= MATCH_TH) ? bi : -1;
    int assigned = (matched >= 0) ? gtl[b * NG + matched] : 0;
    out_matched[t]  = (float)matched;
    out_assigned[t] = (float)assigned;
}

// ------ softmax row stats + conservative logit threshold (one wave/row) ----
__global__ void rowstats_kernel(const float* __restrict__ logits,
                                float* __restrict__ rowmax,
                                float* __restrict__ rowsum,
                                float* __restrict__ thr) {
    int gw = (blockIdx.x * blockDim.x + threadIdx.x) >> 6;
    int lane = threadIdx.x & 63;
    if (gw >= NB * NN) return;
    const float* row = logits + (size_t)gw * NC;
    float m = -INFINITY;
    for (int c = lane; c < NC; c += 64) m = fmaxf(m, row[c]);
    for (int o = 32; o; o >>= 1) m = fmaxf(m, __shfl_down(m, o));
    m = __shfl(m, 0);
    float s = 0.0f;
    for (int c = lane; c < NC; c += 64) s = __fadd_rn(s, expf(__fsub_rn(row[c], m)));
    for (int o = 32; o; o >>= 1) s = __fadd_rn(s, __shfl_down(s, o));
    if (lane == 0) {
        rowmax[gw] = m; rowsum[gw] = s;
        // conservative: score>0.05 => l > m + log(0.04*s)   (0.223 logit slack)
        thr[gw] = __fadd_rn(m, logf(__fmul_rn(0.04f, s)));
    }
}

// ---- single-pass fill: cheap logit pre-filter, rare-path exact decode -----
__global__ void fill_kernel(const float* __restrict__ logits,
                            const float* __restrict__ reg,
                            const float* __restrict__ props,
                            const float* __restrict__ rowmax,
                            const float* __restrict__ rowsum,
                            const float* __restrict__ thr,
                            int* __restrict__ cursors,
                            float* __restrict__ e_sc, float* __restrict__ e_x1,
                            float* __restrict__ e_y1, float* __restrict__ e_x2,
                            float* __restrict__ e_y2, float* __restrict__ e_id,
                            int slots) {
    const int PER = NN * NCLS;
    int t = blockIdx.x * blockDim.x + threadIdx.x;
    if (t >= NB * PER) return;
    int b = t / PER, r = t % PER;
    int n = r / NCLS, c = r % NCLS + 1;
    int row = b * NN + n;

    float l = logits[(size_t)row * NC + c];
    if (l > thr[row]) {   // rare (~4%) — execz skips whole body per wave
        // exact score (identical op sequence to reference path)
        float score = __fdiv_rn(expf(__fsub_rn(l, rowmax[row])), rowsum[row]);

        const float4 p = *reinterpret_cast<const float4*>(props + (size_t)row * 4);
        float w  = __fsub_rn(p.z, p.x);
        float h  = __fsub_rn(p.w, p.y);
        float cx = __fadd_rn(p.x, __fmul_rn(0.5f, w));
        float cy = __fadd_rn(p.y, __fmul_rn(0.5f, h));

        const float4 r4 = *reinterpret_cast<const float4*>(
            reg + (size_t)row * (NC * 4) + (size_t)c * 4);
        float dx = __fdiv_rn(r4.x, 10.0f);
        float dy = __fdiv_rn(r4.y, 10.0f);
        float dw = fminf(__fdiv_rn(r4.z, 5.0f), BBOX_CLIP);
        float dh = fminf(__fdiv_rn(r4.w, 5.0f), BBOX_CLIP);

        float pcx = __fadd_rn(__fmul_rn(dx, w), cx);
        float pcy = __fadd_rn(__fmul_rn(dy, h), cy);
        float pw  = __fmul_rn(expf(dw), w);
        float ph  = __fmul_rn(expf(dh), h);

        float x1 = __fsub_rn(pcx, __fmul_rn(0.5f, pw));
        float y1 = __fsub_rn(pcy, __fmul_rn(0.5f, ph));
        float x2 = __fadd_rn(pcx, __fmul_rn(0.5f, pw));
        float y2 = __fadd_rn(pcy, __fmul_rn(0.5f, ph));
        x1 = fminf(fmaxf(x1, 0.0f), 800.0f);
        y1 = fminf(fmaxf(y1, 0.0f), 800.0f);
        x2 = fminf(fmaxf(x2, 0.0f), 800.0f);
        y2 = fminf(fmaxf(y2, 0.0f), 800.0f);

        float ws_ = __fsub_rn(x2, x1);
        float hs_ = __fsub_rn(y2, y1);
        if ((score > SCORE_TH) && (ws_ >= MIN_SIZE) && (hs_ >= MIN_SIZE)) {
            int g = b * NCLS + (c - 1);
            int pos = atomicAdd(&cursors[g * CUR_STRIDE], 1);
            if (pos < slots) {
                size_t idx = (size_t)g * slots + pos;
                e_sc[idx] = score; e_x1[idx] = x1; e_y1[idx] = y1;
                e_x2[idx] = x2;    e_y2[idx] = y2; e_id[idx] = (float)r;
            }
        }
    }
}

// ---------------- register-resident wave NMS ------------------------------
template <int CAP>
__device__ __forceinline__ void nms_reg(
    int g, int n, const float* __restrict__ SC, const float* __restrict__ X1,
    const float* __restrict__ Y1, const float* __restrict__ X2,
    const float* __restrict__ Y2, const float* __restrict__ ID,
    float tb, float cls, float* __restrict__ selbuf, int* __restrict__ selcnt)
{
    int lane = threadIdx.x;
    float s[CAP], x1[CAP], y1[CAP], x2[CAP], y2[CAP], idv[CAP], ar[CAP];
#pragma unroll
    for (int j = 0; j < CAP; ++j) {
        int sl = lane + j * 64;
        bool v = sl < n;
        s[j]   = v ? SC[sl] : -INFINITY;
        x1[j]  = v ? X1[sl] : 0.0f;
        y1[j]  = v ? Y1[sl] : 0.0f;
        x2[j]  = v ? X2[sl] : 0.0f;
        y2[j]  = v ? Y2[sl] : 0.0f;
        idv[j] = v ? ID[sl] : INFINITY;
        float ox1 = __fadd_rn(x1[j], tb), oy1 = __fadd_rn(y1[j], tb);
        float ox2 = __fadd_rn(x2[j], tb), oy2 = __fadd_rn(y2[j], tb);
        ar[j] = __fmul_rn(__fsub_rn(ox2, ox1), __fsub_rn(oy2, oy1));
    }
    int kout = 0;
    for (int k = 0; k < NK; ++k) {
        float bv = -INFINITY, boi = INFINITY; int bsl = 0;
#pragma unroll
        for (int j = 0; j < CAP; ++j) {
            bool bt = (s[j] > bv) || (s[j] == bv && idv[j] < boi);
            bv = bt ? s[j] : bv; boi = bt ? idv[j] : boi; bsl = bt ? j : bsl;
        }
        int wl = lane;
#pragma unroll
        for (int o = 1; o < 64; o <<= 1) {
            float v2 = __shfl_xor(bv, o); float o2 = __shfl_xor(boi, o);
            int l2 = __shfl_xor(wl, o);
            bool bt = (v2 > bv) || (v2 == bv && o2 < boi);
            bv = bt ? v2 : bv; boi = bt ? o2 : boi; wl = bt ? l2 : wl;
        }
        if (bv == -INFINITY) break;
        float cs = s[0], cx1 = x1[0], cy1 = y1[0], cx2 = x2[0], cy2 = y2[0];
        float cid = idv[0], car = ar[0];
#pragma unroll
        for (int j = 1; j < CAP; ++j) {
            bool pk = (bsl == j);
            cs = pk ? s[j] : cs; cx1 = pk ? x1[j] : cx1; cy1 = pk ? y1[j] : cy1;
            cx2 = pk ? x2[j] : cx2; cy2 = pk ? y2[j] : cy2;
            cid = pk ? idv[j] : cid; car = pk ? ar[j] : car;
        }
        float sx1 = __shfl(cx1, wl), sy1 = __shfl(cy1, wl);
        float sx2 = __shfl(cx2, wl), sy2 = __shfl(cy2, wl);
        float sar = __shfl(car, wl);
        if (lane == wl) {
            float* so = selbuf + ((size_t)g * NK + k) * 8;
            so[0] = cs; so[1] = cx1; so[2] = cy1; so[3] = cx2; so[4] = cy2;
            so[5] = cls; so[6] = cid; so[7] = 0.0f;
        }
        float bx1 = __fadd_rn(sx1, tb), by1 = __fadd_rn(sy1, tb);
        float bx2 = __fadd_rn(sx2, tb), by2 = __fadd_rn(sy2, tb);
#pragma unroll
        for (int j = 0; j < CAP; ++j) {
            float ox1 = __fadd_rn(x1[j], tb), oy1 = __fadd_rn(y1[j], tb);
            float ox2 = __fadd_rn(x2[j], tb), oy2 = __fadd_rn(y2[j], tb);
            float ltx = fmaxf(ox1, bx1), lty = fmaxf(oy1, by1);
            float rbx = fminf(ox2, bx2), rby = fminf(oy2, by2);
            float wx = fmaxf(__fsub_rn(rbx, ltx), 0.0f);
            float wy = fmaxf(__fsub_rn(rby, lty), 0.0f);
            float inter = __fmul_rn(wx, wy);
            float den = __fsub_rn(__fadd_rn(ar[j], sar), inter);
            bool sup = ((double)inter > C_SUP * (double)den);
            s[j] = sup ? -INFINITY : s[j];
        }
        kout = k + 1;
    }
    if (lane == 0) selcnt[g] = kout;
}

// fallback for n > 1024 (not expected on this data)
__device__ void nms_glb(int g, int n, float* __restrict__ SC,
                        const float* __restrict__ X1, const float* __restrict__ Y1,
                        const float* __restrict__ X2, const float* __restrict__ Y2,
                        const float* __restrict__ ID, float tb, float cls,
                        float* __restrict__ selbuf, int* __restrict__ selcnt)
{
    int lane = threadIdx.x;
    int kout = 0;
    for (int k = 0; k < NK; ++k) {
        float bv = -INFINITY, boi = INFINITY; int bi = -1;
        for (int i = lane; i < n; i += 64) {
            float v = SC[i], oi = ID[i];
            if (v > bv || (v == bv && oi < boi)) { bv = v; boi = oi; bi = i; }
        }
        int wl = lane;
        for (int o = 1; o < 64; o <<= 1) {
            float v2 = __shfl_xor(bv, o); float o2 = __shfl_xor(boi, o);
            int l2 = __shfl_xor(wl, o);
            bool bt = (v2 > bv) || (v2 == bv && o2 < boi);
            bv = bt ? v2 : bv; boi = bt ? o2 : boi; wl = bt ? l2 : wl;
        }
        if (bv == -INFINITY) break;
        int wi = __shfl(bi, wl);
        float sx1 = X1[wi], sy1 = Y1[wi], sx2 = X2[wi], sy2 = Y2[wi];
        if (lane == wl) {
            float* so = selbuf + ((size_t)g * NK + k) * 8;
            so[0] = bv; so[1] = sx1; so[2] = sy1; so[3] = sx2; so[4] = sy2;
            so[5] = cls; so[6] = boi; so[7] = 0.0f;
        }
        float bx1 = __fadd_rn(sx1, tb), by1 = __fadd_rn(sy1, tb);
        float bx2 = __fadd_rn(sx2, tb), by2 = __fadd_rn(sy2, tb);
        float sar = __fmul_rn(__fsub_rn(bx2, bx1), __fsub_rn(by2, by1));
        for (int i = lane; i < n; i += 64) {
            float v = SC[i];
            if (v == -INFINITY) continue;
            float ox1 = __fadd_rn(X1[i], tb), oy1 = __fadd_rn(Y1[i], tb);
            float ox2 = __fadd_rn(X2[i], tb), oy2 = __fadd_rn(Y2[i], tb);
            float oar = __fmul_rn(__fsub_rn(ox2, ox1), __fsub_rn(oy2, oy1));
            float ltx = fmaxf(ox1, bx1), lty = fmaxf(oy1, by1);
            float rbx = fminf(ox2, bx2), rby = fminf(oy2, by2);
            float wx = fmaxf(__fsub_rn(rbx, ltx), 0.0f);
            float wy = fmaxf(__fsub_rn(rby, lty), 0.0f);
            float inter = __fmul_rn(wx, wy);
            float den = __fsub_rn(__fadd_rn(oar, sar), inter);
            if ((double)inter > C_SUP * (double)den) SC[i] = -INFINITY;
        }
        kout = k + 1;
    }
    if (lane == 0) selcnt[g] = kout;
}

__global__ __launch_bounds__(64) void bucket_nms_kernel(
    const int* __restrict__ cursors, int slots,
    float* __restrict__ e_sc, const float* __restrict__ e_x1,
    const float* __restrict__ e_y1, const float* __restrict__ e_x2,
    const float* __restrict__ e_y2, const float* __restrict__ e_id,
    float* __restrict__ selbuf, int* __restrict__ selcnt)
{
    int g = blockIdx.x;
    int n = cursors[g * CUR_STRIDE]; if (n > slots) n = slots;
    size_t base = (size_t)g * slots;
    float cls = (float)(g % NCLS + 1);
    float tb = __fmul_rn(cls, 801.0f);
    if (n <= 512)
        nms_reg<8>(g, n, e_sc + base, e_x1 + base, e_y1 + base, e_x2 + base,
                   e_y2 + base, e_id + base, tb, cls, selbuf, selcnt);
    else if (n <= 1024)
        nms_reg<16>(g, n, e_sc + base, e_x1 + base, e_y1 + base, e_x2 + base,
                    e_y2 + base, e_id + base, tb, cls, selbuf, selcnt);
    else
        nms_glb(g, n, e_sc + base, e_x1 + base, e_y1 + base, e_x2 + base,
                e_y2 + base, e_id + base, tb, cls, selbuf, selcnt);
}

// ---------------- merge with head prefetch ---------------------------------
__device__ __forceinline__ void loadkey(const float* __restrict__ selbuf,
                                        int g, int p, int c, float& s, float& i) {
    if (p < c) {
        const float* h = selbuf + ((size_t)g * NK + p) * 8;
        s = h[0]; i = h[6];
    } else { s = -INFINITY; i = INFINITY; }
}

__global__ __launch_bounds__(64) void merge_kernel(
    const float* __restrict__ selbuf, const int* __restrict__ selcnt,
    float* __restrict__ out_dets, float* __restrict__ out_kl) {
    int b = blockIdx.x, lane = threadIdx.x;
    int g0 = b * NCLS + lane;
    int g1 = (lane < NCLS - 64) ? g0 + 64 : -1;
    int c0 = selcnt[g0];
    int c1 = (g1 >= 0) ? selcnt[g1] : 0;
    int p0 = 0, p1 = 0;
    float s0c, i0c, s0n, i0n, s1c, i1c, s1n, i1n;
    loadkey(selbuf, g0, 0, c0, s0c, i0c);
    loadkey(selbuf, g0, 1, c0, s0n, i0n);
    if (g1 >= 0) {
        loadkey(selbuf, g1, 0, c1, s1c, i1c);
        loadkey(selbuf, g1, 1, c1, s1n, i1n);
    } else { s1c = -INFINITY; i1c = INFINITY; s1n = -INFINITY; i1n = INFINITY; }

    for (int k = 0; k < NK; ++k) {
        bool t1 = (s1c > s0c) || (s1c == s0c && i1c < i0c);
        float bs = t1 ? s1c : s0c;
        float bi = t1 ? i1c : i0c;
        int bslot = t1 ? (lane + 64) : lane;
        for (int o = 1; o < 64; o <<= 1) {
            float s2 = __shfl_xor(bs, o); float x2 = __shfl_xor(bi, o);
            int b2 = __shfl_xor(bslot, o);
            bool bt = (s2 > bs) || (s2 == bs && x2 < bi);
            bs = bt ? s2 : bs; bi = bt ? x2 : bi; bslot = bt ? b2 : bslot;
        }
        if (bs == -INFINITY) {
            for (int z = k * 5 + lane; z < NK * 5; z += 64)
                out_dets[(size_t)b * NK * 5 + z] = 0.0f;
            for (int z = k + lane; z < NK; z += 64)
                out_kl[(size_t)b * NK + z] = -1.0f;
            return;
        }
        int owner = bslot & 63;
        if (lane == owner) {
            bool isA = (bslot < 64);
            int g = isA ? g0 : g1;
            int p = isA ? p0 : p1;
            const float* e = selbuf + ((size_t)g * NK + p) * 8;
            size_t o = ((size_t)b * NK + k) * 5;
            out_dets[o + 0] = e[1]; out_dets[o + 1] = e[2];
            out_dets[o + 2] = e[3]; out_dets[o + 3] = e[4];
            out_dets[o + 4] = e[0];
            out_kl[(size_t)b * NK + k] = e[5];
            if (isA) { p0++; s0c = s0n; i0c = i0n; loadkey(selbuf, g0, p0 + 1, c0, s0n, i0n); }
            else     { p1++; s1c = s1n; i1c = i1n; loadkey(selbuf, g1, p1 + 1, c1, s1n, i1n); }
        }
    }
}

extern "C" void kernel_launch(void* const* d_in, const int* in_sizes, int n_in,
                              void* d_out, int out_size, void* d_ws, size_t ws_size,
                              hipStream_t stream) {
    const float* logits = (const float*)d_in[0];
    const float* reg    = (const float*)d_in[1];
    const float* props  = (const float*)d_in[2];
    const float* gtb    = (const float*)d_in[3];
    const int*   gtl    = (const int*)d_in[4];

    float* out          = (float*)d_out;
    float* out_dets     = out;                    // NB*NK*5 = 2000
    float* out_kl       = out + NB * NK * 5;      // NB*NK   = 400
    float* out_assigned = out_kl + NB * NK;       // NB*NN   = 24000
    float* out_matched  = out_assigned + NB * NN; // NB*NN   = 24000

    char* ws = (char*)d_ws;
    int*   cursors = (int*)(ws + 0);              // 360*32*4 = 46080 B
    int*   selcnt  = (int*)(ws + 49152);          // 1440 B
    float* rowmax  = (float*)(ws + 53248);        // 96000 B
    float* rowsum  = (float*)(ws + 151552);       // 96000 B
    float* thr     = (float*)(ws + 249856);       // 96000 B
    float* selbuf  = (float*)(ws + 348160);       // 360*100*8*4 = 1152000 B
    size_t off_ent = 1507328;

    long avail = (long)ws_size - (long)off_ent;
    long per_slot = 6L * 4L * NBUC;               // 8640 B per slot index
    long slotsl = (avail > 0) ? avail / per_slot : 0;
    int slots = (int)((slotsl > SLOTS_MAX) ? SLOTS_MAX : (slotsl < 0 ? 0 : slotsl));

    size_t fsz = (size_t)NBUC * slots;            // floats per field
    float* e_sc = (float*)(ws + off_ent);
    float* e_x1 = e_sc + fsz;
    float* e_y1 = e_x1 + fsz;
    float* e_x2 = e_y1 + fsz;
    float* e_y2 = e_x2 + fsz;
    float* e_id = e_y2 + fsz;

    const int TOT = NB * NN * NCLS;

    matcher_kernel<<<(NB * NN + 511) / 512, 512, 0, stream>>>(
        props, gtb, gtl, out_assigned, out_matched, cursors);
    rowstats_kernel<<<(NB * NN * 64 + 255) / 256, 256, 0, stream>>>(
        logits, rowmax, rowsum, thr);
    fill_kernel<<<(TOT + 255) / 256, 256, 0, stream>>>(
        logits, reg, props, rowmax, rowsum, thr, cursors,
        e_sc, e_x1, e_y1, e_x2, e_y2, e_id, slots);
    bucket_nms_kernel<<<NBUC, 64, 0, stream>>>(
        cursors, slots, e_sc, e_x1, e_y1, e_x2, e_y2, e_id, selbuf, selcnt);
    merge_kernel<<<NB, 64, 0, stream>>>(selbuf, selcnt, out_dets, out_kl);
}

// Round 5
// 198.658 us; speedup vs baseline: 29.4977x; 1.2894x over previous
//
#include <hip/hip_runtime.h>
#include <math.h>

#define NB 4
#define NN 6000
#define NC 91
#define NG 32
#define NK 100
#define NCLS (NC - 1)        /* 90 */
#define NBUC (NB * NCLS)     /* 360 */
#define SLOTS_MAX 2048
#define CUR_STRIDE 32        /* one cursor per 128B line (atomic padding) */
#define PMAX 512             /* fast-path bucket capacity (sort+matrix in LDS) */

#define SCORE_TH 0.05f
#define NMS_TH 0.5f
#define MATCH_TH 0.5f
#define MIN_SIZE 0.01f
#define BBOX_CLIP 4.135166556742356f  /* log(1000/16) */
/* fdiv_rn(inter,den) > 0.5f  <=>  (double)inter > C_SUP*(double)den  (exact) */
#define C_SUP 0.5000000298023223876953125

// ------- matcher (+ zero padded bucket cursors using the whole grid) -------
__global__ __launch_bounds__(512) void matcher_kernel(
    const float* __restrict__ props, const float* __restrict__ gtb,
    const int* __restrict__ gtl, float* __restrict__ out_assigned,
    float* __restrict__ out_matched, int* __restrict__ cursors) {
    int t = blockIdx.x * blockDim.x + threadIdx.x;
    if (t < NBUC * CUR_STRIDE) cursors[t] = 0;
    if (t >= NB * NN) return;
    int b = t / NN;
    const float4 p = *reinterpret_cast<const float4*>(props + (size_t)t * 4);
    float parea = __fmul_rn(__fsub_rn(p.z, p.x), __fsub_rn(p.w, p.y));
    float best = -1.0f; int bi = -1;
    for (int g = 0; g < NG; ++g) {
        const float4 q = *reinterpret_cast<const float4*>(gtb + ((size_t)b * NG + g) * 4);
        float garea = __fmul_rn(__fsub_rn(q.z, q.x), __fsub_rn(q.w, q.y));
        float ltx = fmaxf(q.x, p.x), lty = fmaxf(q.y, p.y);
        float rbx = fminf(q.z, p.z), rby = fminf(q.w, p.w);
        float wx = fmaxf(__fsub_rn(rbx, ltx), 0.0f);
        float wy = fmaxf(__fsub_rn(rby, lty), 0.0f);
        float inter = __fmul_rn(wx, wy);
        float iou = __fdiv_rn(inter, __fsub_rn(__fadd_rn(garea, parea), inter));
        if (iou > best) { best = iou; bi = g; }
    }
    int matched = (best >= MATCH_TH) ? bi : -1;
    int assigned = (matched >= 0) ? gtl[b * NG + matched] : 0;
    out_matched[t]  = (float)matched;
    out_assigned[t] = (float)assigned;
}

// ------ softmax row stats + conservative logit threshold (one wave/row) ----
__global__ void rowstats_kernel(const float* __restrict__ logits,
                                float* __restrict__ rowmax,
                                float* __restrict__ rowsum,
                                float* __restrict__ thr) {
    int gw = (blockIdx.x * blockDim.x + threadIdx.x) >> 6;
    int lane = threadIdx.x & 63;
    if (gw >= NB * NN) return;
    const float* row = logits + (size_t)gw * NC;
    float m = -INFINITY;
    for (int c = lane; c < NC; c += 64) m = fmaxf(m, row[c]);
    for (int o = 32; o; o >>= 1) m = fmaxf(m, __shfl_down(m, o));
    m = __shfl(m, 0);
    float s = 0.0f;
    for (int c = lane; c < NC; c += 64) s = __fadd_rn(s, expf(__fsub_rn(row[c], m)));
    for (int o = 32; o; o >>= 1) s = __fadd_rn(s, __shfl_down(s, o));
    if (lane == 0) {
        rowmax[gw] = m; rowsum[gw] = s;
        // conservative: score>0.05 => l > m + log(0.04*s)   (0.223 logit slack)
        thr[gw] = __fadd_rn(m, logf(__fmul_rn(0.04f, s)));
    }
}

// ---- single-pass fill: cheap logit pre-filter, rare-path exact decode -----
__global__ void fill_kernel(const float* __restrict__ logits,
                            const float* __restrict__ reg,
                            const float* __restrict__ props,
                            const float* __restrict__ rowmax,
                            const float* __restrict__ rowsum,
                            const float* __restrict__ thr,
                            int* __restrict__ cursors,
                            float* __restrict__ e_sc, float* __restrict__ e_x1,
                            float* __restrict__ e_y1, float* __restrict__ e_x2,
                            float* __restrict__ e_y2, float* __restrict__ e_id,
                            int slots) {
    const int PER = NN * NCLS;
    int t = blockIdx.x * blockDim.x + threadIdx.x;
    if (t >= NB * PER) return;
    int b = t / PER, r = t % PER;
    int n = r / NCLS, c = r % NCLS + 1;
    int row = b * NN + n;

    float l = logits[(size_t)row * NC + c];
    if (l > thr[row]) {   // rare (~4%) — execz skips whole body per wave
        float score = __fdiv_rn(expf(__fsub_rn(l, rowmax[row])), rowsum[row]);

        const float4 p = *reinterpret_cast<const float4*>(props + (size_t)row * 4);
        float w  = __fsub_rn(p.z, p.x);
        float h  = __fsub_rn(p.w, p.y);
        float cx = __fadd_rn(p.x, __fmul_rn(0.5f, w));
        float cy = __fadd_rn(p.y, __fmul_rn(0.5f, h));

        const float4 r4 = *reinterpret_cast<const float4*>(
            reg + (size_t)row * (NC * 4) + (size_t)c * 4);
        float dx = __fdiv_rn(r4.x, 10.0f);
        float dy = __fdiv_rn(r4.y, 10.0f);
        float dw = fminf(__fdiv_rn(r4.z, 5.0f), BBOX_CLIP);
        float dh = fminf(__fdiv_rn(r4.w, 5.0f), BBOX_CLIP);

        float pcx = __fadd_rn(__fmul_rn(dx, w), cx);
        float pcy = __fadd_rn(__fmul_rn(dy, h), cy);
        float pw  = __fmul_rn(expf(dw), w);
        float ph  = __fmul_rn(expf(dh), h);

        float x1 = __fsub_rn(pcx, __fmul_rn(0.5f, pw));
        float y1 = __fsub_rn(pcy, __fmul_rn(0.5f, ph));
        float x2 = __fadd_rn(pcx, __fmul_rn(0.5f, pw));
        float y2 = __fadd_rn(pcy, __fmul_rn(0.5f, ph));
        x1 = fminf(fmaxf(x1, 0.0f), 800.0f);
        y1 = fminf(fmaxf(y1, 0.0f), 800.0f);
        x2 = fminf(fmaxf(x2, 0.0f), 800.0f);
        y2 = fminf(fmaxf(y2, 0.0f), 800.0f);

        float ws_ = __fsub_rn(x2, x1);
        float hs_ = __fsub_rn(y2, y1);
        if ((score > SCORE_TH) && (ws_ >= MIN_SIZE) && (hs_ >= MIN_SIZE)) {
            int g = b * NCLS + (c - 1);
            int pos = atomicAdd(&cursors[g * CUR_STRIDE], 1);
            if (pos < slots) {
                size_t idx = (size_t)g * slots + pos;
                e_sc[idx] = score; e_x1[idx] = x1; e_y1[idx] = y1;
                e_x2[idx] = x2;    e_y2[idx] = y2; e_id[idx] = (float)r;
            }
        }
    }
}

// ---------------- wave-serial fallback for n > PMAX (rare/never) -----------
__device__ void nms_glb(int g, int n, float* __restrict__ SC,
                        const float* __restrict__ X1, const float* __restrict__ Y1,
                        const float* __restrict__ X2, const float* __restrict__ Y2,
                        const float* __restrict__ ID, float tb, float cls,
                        float* __restrict__ selbuf, int* __restrict__ selcnt)
{
    int lane = threadIdx.x;
    int kout = 0;
    for (int k = 0; k < NK; ++k) {
        float bv = -INFINITY, boi = INFINITY; int bi = -1;
        for (int i = lane; i < n; i += 64) {
            float v = SC[i], oi = ID[i];
            if (v > bv || (v == bv && oi < boi)) { bv = v; boi = oi; bi = i; }
        }
        int wl = lane;
        for (int o = 1; o < 64; o <<= 1) {
            float v2 = __shfl_xor(bv, o); float o2 = __shfl_xor(boi, o);
            int l2 = __shfl_xor(wl, o);
            bool bt = (v2 > bv) || (v2 == bv && o2 < boi);
            bv = bt ? v2 : bv; boi = bt ? o2 : boi; wl = bt ? l2 : wl;
        }
        if (bv == -INFINITY) break;
        int wi = __shfl(bi, wl);
        float sx1 = X1[wi], sy1 = Y1[wi], sx2 = X2[wi], sy2 = Y2[wi];
        if (lane == wl) {
            float* so = selbuf + ((size_t)g * NK + k) * 8;
            so[0] = bv; so[1] = sx1; so[2] = sy1; so[3] = sx2; so[4] = sy2;
            so[5] = cls; so[6] = boi; so[7] = 0.0f;
        }
        float bx1 = __fadd_rn(sx1, tb), by1 = __fadd_rn(sy1, tb);
        float bx2 = __fadd_rn(sx2, tb), by2 = __fadd_rn(sy2, tb);
        float sar = __fmul_rn(__fsub_rn(bx2, bx1), __fsub_rn(by2, by1));
        for (int i = lane; i < n; i += 64) {
            float v = SC[i];
            if (v == -INFINITY) continue;
            float ox1 = __fadd_rn(X1[i], tb), oy1 = __fadd_rn(Y1[i], tb);
            float ox2 = __fadd_rn(X2[i], tb), oy2 = __fadd_rn(Y2[i], tb);
            float oar = __fmul_rn(__fsub_rn(ox2, ox1), __fsub_rn(oy2, oy1));
            float ltx = fmaxf(ox1, bx1), lty = fmaxf(oy1, by1);
            float rbx = fminf(ox2, bx2), rby = fminf(oy2, by2);
            float wx = fmaxf(__fsub_rn(rbx, ltx), 0.0f);
            float wy = fmaxf(__fsub_rn(rby, lty), 0.0f);
            float inter = __fmul_rn(wx, wy);
            float den = __fsub_rn(__fadd_rn(oar, sar), inter);
            if ((double)inter > C_SUP * (double)den) SC[i] = -INFINITY;
        }
        kout = k + 1;
    }
    if (lane == 0) selcnt[g] = kout;
}

// ------- sort + suppression-matrix + bit-sweep NMS (one block/bucket) ------
__global__ __launch_bounds__(256) void bucket_nms_kernel(
    const int* __restrict__ cursors, int slots,
    float* __restrict__ e_sc, const float* __restrict__ e_x1,
    const float* __restrict__ e_y1, const float* __restrict__ e_x2,
    const float* __restrict__ e_y2, const float* __restrict__ e_id,
    float* __restrict__ selbuf, int* __restrict__ selcnt)
{
    int g = blockIdx.x;
    int n = cursors[g * CUR_STRIDE]; if (n > slots) n = slots;
    size_t base = (size_t)g * slots;
    float cls = (float)(g % NCLS + 1);
    float tb = __fmul_rn(cls, 801.0f);
    int tid = threadIdx.x;

    if (n > PMAX) {  // fallback path: wave 0 serial (no barriers inside)
        if (tid < 64)
            nms_glb(g, n, e_sc + base, e_x1 + base, e_y1 + base,
                    e_x2 + base, e_y2 + base, e_id + base, tb, cls,
                    selbuf, selcnt);
        return;
    }
    if (n == 0) { if (tid == 0) selcnt[g] = 0; return; }

    __shared__ unsigned long long skey[PMAX];
    __shared__ int sperm[PMAX];
    __shared__ float sox1[PMAX], soy1[PMAX], sox2[PMAX], soy2[PMAX], soar[PMAX];
    __shared__ unsigned long long dmask[PMAX * 8];
    __shared__ int accepted[NK];
    __shared__ int s_kcount;

    int P = 64; while (P < n) P <<= 1;

    // load packed keys: (score_bits<<32)|~idx  — u64 max == (score desc, idx asc)
    for (int i = tid; i < P; i += 256) {
        if (i < n) {
            float sc = e_sc[base + i];
            unsigned int r = (unsigned int)e_id[base + i];  // exact: r < 2^24
            skey[i] = ((unsigned long long)__float_as_uint(sc) << 32)
                    | (unsigned long long)(~r);
        } else skey[i] = 0ull;
        sperm[i] = i;
    }
    // bitonic sort, descending
    for (int k = 2; k <= P; k <<= 1) {
        for (int j = k >> 1; j > 0; j >>= 1) {
            __syncthreads();
            for (int t = tid; t < (P >> 1); t += 256) {
                int i = ((t & ~(j - 1)) << 1) | (t & (j - 1));
                int l = i | j;
                bool desc = ((i & k) == 0);
                unsigned long long a = skey[i], c = skey[l];
                bool sw = desc ? (a < c) : (a > c);
                if (sw) {
                    skey[i] = c; skey[l] = a;
                    int tp = sperm[i]; sperm[i] = sperm[l]; sperm[l] = tp;
                }
            }
        }
    }
    __syncthreads();
    // materialize offset coords + areas in sorted order
    for (int i = tid; i < n; i += 256) {
        int sl = sperm[i];
        float ox1 = __fadd_rn(e_x1[base + sl], tb);
        float oy1 = __fadd_rn(e_y1[base + sl], tb);
        float ox2 = __fadd_rn(e_x2[base + sl], tb);
        float oy2 = __fadd_rn(e_y2[base + sl], tb);
        sox1[i] = ox1; soy1[i] = oy1; sox2[i] = ox2; soy2[i] = oy2;
        soar[i] = __fmul_rn(__fsub_rn(ox2, ox1), __fsub_rn(oy2, oy1));
    }
    __syncthreads();
    int nblk = (n + 63) >> 6;
    // suppression matrix: dmask[i][blk] bits j suppressed by i (blk >= i/64)
    for (int t = tid; t < n * nblk; t += 256) {
        int i = t / nblk, blk = t % nblk;
        if (blk < (i >> 6)) continue;   // lower blocks never consulted
        float bx1 = sox1[i], by1 = soy1[i], bx2 = sox2[i], by2 = soy2[i];
        float bar = soar[i];
        unsigned long long bits = 0ull;
        int j0 = blk << 6;
        int jend = n - j0; if (jend > 64) jend = 64;
        for (int jj = 0; jj < jend; ++jj) {
            int j = j0 + jj;
            float ltx = fmaxf(sox1[j], bx1), lty = fmaxf(soy1[j], by1);
            float rbx = fminf(sox2[j], bx2), rby = fminf(soy2[j], by2);
            float wx = fmaxf(__fsub_rn(rbx, ltx), 0.0f);
            float wy = fmaxf(__fsub_rn(rby, lty), 0.0f);
            float inter = __fmul_rn(wx, wy);
            float den = __fsub_rn(__fadd_rn(soar[j], bar), inter);
            if ((double)inter > C_SUP * (double)den) bits |= (1ull << jj);
        }
        dmask[i * 8 + blk] = bits;
    }
    __syncthreads();
    // serial sweep: wave 0; lanes 0..7 own the alive bit-words in registers
    if (tid < 64) {
        int lane = tid;
        unsigned long long alive = 0ull;
        if (lane < nblk) {
            int rem = n - (lane << 6);
            alive = (rem >= 64) ? ~0ull : ((1ull << rem) - 1ull);
        }
        int kout = 0, cur = 0;
        while (kout < NK) {
            unsigned long long m = alive;
            int lo = lane << 6;
            if (lo + 63 < cur) m = 0ull;
            else if (cur > lo) m &= ~((1ull << (cur - lo)) - 1ull);
            int cand = m ? (lo + __ffsll((unsigned long long)m) - 1) : 0x7FFFFFFF;
            for (int o = 1; o < 8; o <<= 1) {
                int c2 = __shfl_xor(cand, o);
                cand = (c2 < cand) ? c2 : cand;
            }
            cand = __shfl(cand, 0);
            if (cand == 0x7FFFFFFF) break;
            if (lane == 0) accepted[kout] = cand;
            kout++;
            if (lane < nblk) alive &= ~dmask[cand * 8 + lane];
            cur = cand + 1;
        }
        if (lane == 0) { selcnt[g] = kout; s_kcount = kout; }
    }
    __syncthreads();
    // parallel output write (sorted desc by construction)
    int kc = s_kcount;
    for (int idx = tid; idx < kc; idx += 256) {
        int i = accepted[idx];
        int sl = sperm[i];
        unsigned long long key = skey[i];
        float score = __uint_as_float((unsigned int)(key >> 32));
        unsigned int r = ~((unsigned int)key);
        float* so = selbuf + ((size_t)g * NK + idx) * 8;
        so[0] = score;
        so[1] = e_x1[base + sl]; so[2] = e_y1[base + sl];
        so[3] = e_x2[base + sl]; so[4] = e_y2[base + sl];
        so[5] = cls; so[6] = (float)r; so[7] = 0.0f;
    }
}

// ---------------- merge with u64 keys + head prefetch ----------------------
__device__ __forceinline__ unsigned long long mkey(const float* __restrict__ h) {
    unsigned int sb = __float_as_uint(h[0]);
    unsigned int r = (unsigned int)h[6];
    return ((unsigned long long)sb << 32) | (unsigned long long)(~r);
}
__device__ __forceinline__ void loadkey(const float* __restrict__ selbuf,
                                        int g, int p, int c,
                                        unsigned long long& key) {
    key = (p < c) ? mkey(selbuf + ((size_t)g * NK + p) * 8) : 0ull;
}

__global__ __launch_bounds__(64) void merge_kernel(
    const float* __restrict__ selbuf, const int* __restrict__ selcnt,
    float* __restrict__ out_dets, float* __restrict__ out_kl) {
    int b = blockIdx.x, lane = threadIdx.x;
    int g0 = b * NCLS + lane;
    int g1 = (lane < NCLS - 64) ? g0 + 64 : -1;
    int c0 = selcnt[g0];
    int c1 = (g1 >= 0) ? selcnt[g1] : 0;
    int p0 = 0, p1 = 0;
    unsigned long long k0c, k0n, k1c = 0ull, k1n = 0ull;
    loadkey(selbuf, g0, 0, c0, k0c);
    loadkey(selbuf, g0, 1, c0, k0n);
    if (g1 >= 0) {
        loadkey(selbuf, g1, 0, c1, k1c);
        loadkey(selbuf, g1, 1, c1, k1n);
    }

    for (int k = 0; k < NK; ++k) {
        bool t1 = (k1c > k0c);
        unsigned long long bk = t1 ? k1c : k0c;
        int bslot = t1 ? (lane + 64) : lane;
        for (int o = 1; o < 64; o <<= 1) {
            unsigned long long k2 = __shfl_xor(bk, o);
            int b2 = __shfl_xor(bslot, o);
            if (k2 > bk) { bk = k2; bslot = b2; }
        }
        if (bk == 0ull) {
            for (int z = k * 5 + lane; z < NK * 5; z += 64)
                out_dets[(size_t)b * NK * 5 + z] = 0.0f;
            for (int z = k + lane; z < NK; z += 64)
                out_kl[(size_t)b * NK + z] = -1.0f;
            return;
        }
        int owner = bslot & 63;
        if (lane == owner) {
            bool isA = (bslot < 64);
            int g = isA ? g0 : g1;
            int p = isA ? p0 : p1;
            const float* e = selbuf + ((size_t)g * NK + p) * 8;
            size_t o = ((size_t)b * NK + k) * 5;
            out_dets[o + 0] = e[1]; out_dets[o + 1] = e[2];
            out_dets[o + 2] = e[3]; out_dets[o + 3] = e[4];
            out_dets[o + 4] = e[0];
            out_kl[(size_t)b * NK + k] = e[5];
            if (isA) { p0++; k0c = k0n; loadkey(selbuf, g0, p0 + 1, c0, k0n); }
            else     { p1++; k1c = k1n; loadkey(selbuf, g1, p1 + 1, c1, k1n); }
        }
    }
}

extern "C" void kernel_launch(void* const* d_in, const int* in_sizes, int n_in,
                              void* d_out, int out_size, void* d_ws, size_t ws_size,
                              hipStream_t stream) {
    const float* logits = (const float*)d_in[0];
    const float* reg    = (const float*)d_in[1];
    const float* props  = (const float*)d_in[2];
    const float* gtb    = (const float*)d_in[3];
    const int*   gtl    = (const int*)d_in[4];

    float* out          = (float*)d_out;
    float* out_dets     = out;                    // NB*NK*5 = 2000
    float* out_kl       = out + NB * NK * 5;      // NB*NK   = 400
    float* out_assigned = out_kl + NB * NK;       // NB*NN   = 24000
    float* out_matched  = out_assigned + NB * NN; // NB*NN   = 24000

    char* ws = (char*)d_ws;
    int*   cursors = (int*)(ws + 0);              // 360*32*4 = 46080 B
    int*   selcnt  = (int*)(ws + 49152);          // 1440 B
    float* rowmax  = (float*)(ws + 53248);        // 96000 B
    float* rowsum  = (float*)(ws + 151552);       // 96000 B
    float* thr     = (float*)(ws + 249856);       // 96000 B
    float* selbuf  = (float*)(ws + 348160);       // 360*100*8*4 = 1152000 B
    size_t off_ent = 1507328;

    long avail = (long)ws_size - (long)off_ent;
    long per_slot = 6L * 4L * NBUC;               // 8640 B per slot index
    long slotsl = (avail > 0) ? avail / per_slot : 0;
    int slots = (int)((slotsl > SLOTS_MAX) ? SLOTS_MAX : (slotsl < 0 ? 0 : slotsl));

    size_t fsz = (size_t)NBUC * slots;            // floats per field
    float* e_sc = (float*)(ws + off_ent);
    float* e_x1 = e_sc + fsz;
    float* e_y1 = e_x1 + fsz;
    float* e_x2 = e_y1 + fsz;
    float* e_y2 = e_x2 + fsz;
    float* e_id = e_y2 + fsz;

    const int TOT = NB * NN * NCLS;

    matcher_kernel<<<(NB * NN + 511) / 512, 512, 0, stream>>>(
        props, gtb, gtl, out_assigned, out_matched, cursors);
    rowstats_kernel<<<(NB * NN * 64 + 255) / 256, 256, 0, stream>>>(
        logits, rowmax, rowsum, thr);
    fill_kernel<<<(TOT + 255) / 256, 256, 0, stream>>>(
        logits, reg, props, rowmax, rowsum, thr, cursors,
        e_sc, e_x1, e_y1, e_x2, e_y2, e_id, slots);
    bucket_nms_kernel<<<NBUC, 256, 0, stream>>>(
        cursors, slots, e_sc, e_x1, e_y1, e_x2, e_y2, e_id, selbuf, selcnt);
    merge_kernel<<<NB, 64, 0, stream>>>(selbuf, selcnt, out_dets, out_kl);
}

// Round 6
// 195.052 us; speedup vs baseline: 30.0431x; 1.0185x over previous
//
#include <hip/hip_runtime.h>
#include <math.h>

#define NB 4
#define NN 6000
#define NC 91
#define NG 32
#define NK 100
#define NCLS (NC - 1)        /* 90 */
#define NBUC (NB * NCLS)     /* 360 */
#define SLOTS_MAX 2048
#define CUR_STRIDE 32        /* one cursor per 128B line (atomic padding) */
#define PMAX 512             /* fast-path bucket capacity */
#define MP 2048              /* merge fast-path capacity per image */
#define RS_BLOCKS 6000       /* 24000 rows / 4 waves per block */

#define SCORE_TH 0.05f
#define NMS_TH 0.5f
#define MATCH_TH 0.5f
#define MIN_SIZE 0.01f
#define BBOX_CLIP 4.135166556742356f  /* log(1000/16) */
/* fdiv_rn(inter,den) > 0.5f  <=>  (double)inter > C_SUP*(double)den  (exact) */
#define C_SUP 0.5000000298023223876953125

// ---------------- decode (identical op sequence to rounds 1-5) -------------
__device__ __forceinline__ bool decode_one(
    const float* __restrict__ reg, const float* __restrict__ props,
    float l, float m, float s0, int row, int c, float out[5])
{
    float score = __fdiv_rn(expf(__fsub_rn(l, m)), s0);

    const float4 p = *reinterpret_cast<const float4*>(props + (size_t)row * 4);
    float w  = __fsub_rn(p.z, p.x);
    float h  = __fsub_rn(p.w, p.y);
    float cx = __fadd_rn(p.x, __fmul_rn(0.5f, w));
    float cy = __fadd_rn(p.y, __fmul_rn(0.5f, h));

    const float4 r4 = *reinterpret_cast<const float4*>(
        reg + (size_t)row * (NC * 4) + (size_t)c * 4);
    float dx = __fdiv_rn(r4.x, 10.0f);
    float dy = __fdiv_rn(r4.y, 10.0f);
    float dw = fminf(__fdiv_rn(r4.z, 5.0f), BBOX_CLIP);
    float dh = fminf(__fdiv_rn(r4.w, 5.0f), BBOX_CLIP);

    float pcx = __fadd_rn(__fmul_rn(dx, w), cx);
    float pcy = __fadd_rn(__fmul_rn(dy, h), cy);
    float pw  = __fmul_rn(expf(dw), w);
    float ph  = __fmul_rn(expf(dh), h);

    float x1 = __fsub_rn(pcx, __fmul_rn(0.5f, pw));
    float y1 = __fsub_rn(pcy, __fmul_rn(0.5f, ph));
    float x2 = __fadd_rn(pcx, __fmul_rn(0.5f, pw));
    float y2 = __fadd_rn(pcy, __fmul_rn(0.5f, ph));
    x1 = fminf(fmaxf(x1, 0.0f), 800.0f);
    y1 = fminf(fmaxf(y1, 0.0f), 800.0f);
    x2 = fminf(fmaxf(x2, 0.0f), 800.0f);
    y2 = fminf(fmaxf(y2, 0.0f), 800.0f);

    out[0] = score; out[1] = x1; out[2] = y1; out[3] = x2; out[4] = y2;
    float ws_ = __fsub_rn(x2, x1);
    float hs_ = __fsub_rn(y2, y1);
    return (score > SCORE_TH) && (ws_ >= MIN_SIZE) && (hs_ >= MIN_SIZE);
}

// ---- fused: softmax stats + in-register prefilter + fill  |  matcher ------
__global__ __launch_bounds__(256) void fused_kernel(
    const float* __restrict__ logits, const float* __restrict__ reg,
    const float* __restrict__ props, const float* __restrict__ gtb,
    const int* __restrict__ gtl,
    float* __restrict__ out_assigned, float* __restrict__ out_matched,
    int* __restrict__ cursors,
    float* __restrict__ e_sc, float* __restrict__ e_x1,
    float* __restrict__ e_y1, float* __restrict__ e_x2,
    float* __restrict__ e_y2, float* __restrict__ e_id, int slots)
{
    int bid = blockIdx.x;
    if (bid < RS_BLOCKS) {
        int wid = threadIdx.x >> 6, lane = threadIdx.x & 63;
        int row = bid * 4 + wid;                 // [0, 24000)
        const float* rp = logits + (size_t)row * NC;
        float l0 = rp[lane];
        float l1 = (lane < NC - 64) ? rp[64 + lane] : -INFINITY;
        // max: same sequential-then-tree order as previous rowstats
        float m = fmaxf(fmaxf(-INFINITY, l0), l1);
        for (int o = 32; o; o >>= 1) m = fmaxf(m, __shfl_down(m, o));
        m = __shfl(m, 0);
        float s = __fadd_rn(__fadd_rn(0.0f, expf(__fsub_rn(l0, m))),
                            expf(__fsub_rn(l1, m)));   // exp(-inf)=0 exact
        for (int o = 32; o; o >>= 1) s = __fadd_rn(s, __shfl_down(s, o));
        float s0 = __shfl(s, 0);
        // conservative prefilter: score>0.05 => l > m + log(0.04*s)
        float thr = __fadd_rn(m, logf(__fmul_rn(0.04f, s0)));

        int b = row / NN;
        int nprop = row - b * NN;

        // candidate 1: class c = lane (skip background c==0)
        if (lane >= 1 && l0 > thr) {
            float o[5];
            if (decode_one(reg, props, l0, m, s0, row, lane, o)) {
                int c = lane;
                int g = b * NCLS + (c - 1);
                int pos = atomicAdd(&cursors[g * CUR_STRIDE], 1);
                if (pos < slots) {
                    size_t idx = (size_t)g * slots + pos;
                    e_sc[idx] = o[0]; e_x1[idx] = o[1]; e_y1[idx] = o[2];
                    e_x2[idx] = o[3]; e_y2[idx] = o[4];
                    e_id[idx] = (float)(nprop * NCLS + (c - 1));
                }
            }
        }
        // candidate 2: class c = lane + 64 (lanes 0..26)
        if (lane < NC - 64 && l1 > thr) {
            float o[5];
            int c = lane + 64;
            if (decode_one(reg, props, l1, m, s0, row, c, o)) {
                int g = b * NCLS + (c - 1);
                int pos = atomicAdd(&cursors[g * CUR_STRIDE], 1);
                if (pos < slots) {
                    size_t idx = (size_t)g * slots + pos;
                    e_sc[idx] = o[0]; e_x1[idx] = o[1]; e_y1[idx] = o[2];
                    e_x2[idx] = o[3]; e_y2[idx] = o[4];
                    e_id[idx] = (float)(nprop * NCLS + (c - 1));
                }
            }
        }
    } else {
        // ---- matcher blocks ----
        int t = (bid - RS_BLOCKS) * 256 + threadIdx.x;
        if (t >= NB * NN) return;
        int b = t / NN;
        const float4 p = *reinterpret_cast<const float4*>(props + (size_t)t * 4);
        float parea = __fmul_rn(__fsub_rn(p.z, p.x), __fsub_rn(p.w, p.y));
        float best = -1.0f; int bi = -1;
        for (int g = 0; g < NG; ++g) {
            const float4 q = *reinterpret_cast<const float4*>(gtb + ((size_t)b * NG + g) * 4);
            float garea = __fmul_rn(__fsub_rn(q.z, q.x), __fsub_rn(q.w, q.y));
            float ltx = fmaxf(q.x, p.x), lty = fmaxf(q.y, p.y);
            float rbx = fminf(q.z, p.z), rby = fminf(q.w, p.w);
            float wx = fmaxf(__fsub_rn(rbx, ltx), 0.0f);
            float wy = fmaxf(__fsub_rn(rby, lty), 0.0f);
            float inter = __fmul_rn(wx, wy);
            float iou = __fdiv_rn(inter, __fsub_rn(__fadd_rn(garea, parea), inter));
            if (iou > best) { best = iou; bi = g; }
        }
        int matched = (best >= MATCH_TH) ? bi : -1;
        int assigned = (matched >= 0) ? gtl[b * NG + matched] : 0;
        out_matched[t]  = (float)matched;
        out_assigned[t] = (float)assigned;
    }
}

// ---------------- wave-serial fallback for n > PMAX (never expected) -------
__device__ void nms_glb(int g, int n, float* __restrict__ SC,
                        const float* __restrict__ X1, const float* __restrict__ Y1,
                        const float* __restrict__ X2, const float* __restrict__ Y2,
                        const float* __restrict__ ID, float tb, float cls,
                        float* __restrict__ selbuf, int* __restrict__ selcnt)
{
    int lane = threadIdx.x;
    int kout = 0;
    for (int k = 0; k < NK; ++k) {
        float bv = -INFINITY, boi = INFINITY; int bi = -1;
        for (int i = lane; i < n; i += 64) {
            float v = SC[i], oi = ID[i];
            if (v > bv || (v == bv && oi < boi)) { bv = v; boi = oi; bi = i; }
        }
        int wl = lane;
        for (int o = 1; o < 64; o <<= 1) {
            float v2 = __shfl_xor(bv, o); float o2 = __shfl_xor(boi, o);
            int l2 = __shfl_xor(wl, o);
            bool bt = (v2 > bv) || (v2 == bv && o2 < boi);
            bv = bt ? v2 : bv; boi = bt ? o2 : boi; wl = bt ? l2 : wl;
        }
        if (bv == -INFINITY) break;
        int wi = __shfl(bi, wl);
        float sx1 = X1[wi], sy1 = Y1[wi], sx2 = X2[wi], sy2 = Y2[wi];
        if (lane == wl) {
            float* so = selbuf + ((size_t)g * NK + k) * 8;
            so[0] = bv; so[1] = sx1; so[2] = sy1; so[3] = sx2; so[4] = sy2;
            so[5] = cls; so[6] = boi; so[7] = 0.0f;
        }
        float bx1 = __fadd_rn(sx1, tb), by1 = __fadd_rn(sy1, tb);
        float bx2 = __fadd_rn(sx2, tb), by2 = __fadd_rn(sy2, tb);
        float sar = __fmul_rn(__fsub_rn(bx2, bx1), __fsub_rn(by2, by1));
        for (int i = lane; i < n; i += 64) {
            float v = SC[i];
            if (v == -INFINITY) continue;
            float ox1 = __fadd_rn(X1[i], tb), oy1 = __fadd_rn(Y1[i], tb);
            float ox2 = __fadd_rn(X2[i], tb), oy2 = __fadd_rn(Y2[i], tb);
            float oar = __fmul_rn(__fsub_rn(ox2, ox1), __fsub_rn(oy2, oy1));
            float ltx = fmaxf(ox1, bx1), lty = fmaxf(oy1, by1);
            float rbx = fminf(ox2, bx2), rby = fminf(oy2, by2);
            float wx = fmaxf(__fsub_rn(rbx, ltx), 0.0f);
            float wy = fmaxf(__fsub_rn(rby, lty), 0.0f);
            float inter = __fmul_rn(wx, wy);
            float den = __fsub_rn(__fadd_rn(oar, sar), inter);
            if ((double)inter > C_SUP * (double)den) SC[i] = -INFINITY;
        }
        kout = k + 1;
    }
    if (lane == 0) selcnt[g] = kout;
}

__device__ __forceinline__ float sel8(const float a[8], int j) {
    float r = a[0];
#pragma unroll
    for (int i = 1; i < 8; ++i) r = (j == i) ? a[i] : r;
    return r;
}

// -------- sort (u32-split bitonic) + register-resident sorted sweep --------
__global__ __launch_bounds__(64) void bucket_nms_kernel(
    const int* __restrict__ cursors, int slots,
    float* __restrict__ e_sc, const float* __restrict__ e_x1,
    const float* __restrict__ e_y1, const float* __restrict__ e_x2,
    const float* __restrict__ e_y2, const float* __restrict__ e_id,
    float* __restrict__ selbuf, int* __restrict__ selcnt)
{
    int g = blockIdx.x;
    int n = cursors[g * CUR_STRIDE]; if (n > slots) n = slots;
    int tid = threadIdx.x;
    if (n == 0) { if (tid == 0) selcnt[g] = 0; return; }
    size_t base = (size_t)g * slots;
    float cls = (float)(g % NCLS + 1);
    float tb = __fmul_rn(cls, 801.0f);

    if (n > PMAX) {
        nms_glb(g, n, e_sc + base, e_x1 + base, e_y1 + base,
                e_x2 + base, e_y2 + base, e_id + base, tb, cls, selbuf, selcnt);
        return;
    }

    __shared__ unsigned skhi[PMAX], sklo[PMAX], sperm[PMAX];
    int P = 64; while (P < n) P <<= 1;

    for (int i = tid; i < P; i += 64) {
        if (i < n) {
            skhi[i] = __float_as_uint(e_sc[base + i]);
            sklo[i] = ~((unsigned)e_id[base + i]);   // u64 max == (score desc, idx asc)
        } else { skhi[i] = 0u; sklo[i] = 0u; }
        sperm[i] = i;
    }
    __syncthreads();
    // bitonic sort desc on (skhi,sklo); u32 arrays => <=2-way bank alias (free)
    for (int k = 2; k <= P; k <<= 1) {
        for (int j = k >> 1; j > 0; j >>= 1) {
            for (int t = tid; t < (P >> 1); t += 64) {
                int i = ((t & ~(j - 1)) << 1) | (t & (j - 1));
                int l = i | j;
                unsigned ah = skhi[i], al = sklo[i], ch = skhi[l], cl_ = sklo[l];
                bool alt = (ah < ch) || (ah == ch && al < cl_);
                bool agt = (ah > ch) || (ah == ch && al > cl_);
                bool sw = ((i & k) == 0) ? alt : agt;
                if (sw) {
                    skhi[i] = ch; sklo[i] = cl_; skhi[l] = ah; sklo[l] = al;
                    unsigned tp = sperm[i]; sperm[i] = sperm[l]; sperm[l] = tp;
                }
            }
            __syncthreads();
        }
    }
    // gather 8 sorted entries per lane (chunk layout: lane owns [tid*8, tid*8+8))
    float ox1[8], oy1[8], ox2[8], oy2[8], oar[8];
    unsigned alive = 0;
#pragma unroll
    for (int j = 0; j < 8; ++j) {
        int sidx = tid * 8 + j;
        if (sidx < n) {
            int sl = (int)sperm[sidx];
            ox1[j] = __fadd_rn(e_x1[base + sl], tb);
            oy1[j] = __fadd_rn(e_y1[base + sl], tb);
            ox2[j] = __fadd_rn(e_x2[base + sl], tb);
            oy2[j] = __fadd_rn(e_y2[base + sl], tb);
            oar[j] = __fmul_rn(__fsub_rn(ox2[j], ox1[j]), __fsub_rn(oy2[j], oy1[j]));
            alive |= 1u << j;
        } else {
            ox1[j] = 0.f; oy1[j] = 0.f; ox2[j] = 0.f; oy2[j] = 0.f; oar[j] = 0.f;
        }
    }
    // sweep: first-alive in sorted order == greedy argmax
    int kout = 0;
    while (kout < NK) {
        unsigned long long bal = __ballot(alive != 0u);
        if (!bal) break;
        int fl = (int)(__ffsll(bal) - 1);
        unsigned am = __shfl(alive, fl);
        int js = __ffs(am) - 1;                     // uniform
        float bx1 = __shfl(sel8(ox1, js), fl);
        float by1 = __shfl(sel8(oy1, js), fl);
        float bx2 = __shfl(sel8(ox2, js), fl);
        float by2 = __shfl(sel8(oy2, js), fl);
        float bar = __shfl(sel8(oar, js), fl);
        if (tid == fl) {
            int sl = (int)sperm[tid * 8 + js];
            float* so = selbuf + ((size_t)g * NK + kout) * 8;
            so[0] = e_sc[base + sl];
            so[1] = e_x1[base + sl]; so[2] = e_y1[base + sl];
            so[3] = e_x2[base + sl]; so[4] = e_y2[base + sl];
            so[5] = cls; so[6] = e_id[base + sl]; so[7] = 0.0f;
        }
        kout++;
        unsigned kill = 0;
#pragma unroll
        for (int j = 0; j < 8; ++j) {
            float ltx = fmaxf(ox1[j], bx1), lty = fmaxf(oy1[j], by1);
            float rbx = fminf(ox2[j], bx2), rby = fminf(oy2[j], by2);
            float wx = fmaxf(__fsub_rn(rbx, ltx), 0.0f);
            float wy = fmaxf(__fsub_rn(rby, lty), 0.0f);
            float inter = __fmul_rn(wx, wy);
            float den = __fsub_rn(__fadd_rn(oar[j], bar), inter);
            if ((double)inter > C_SUP * (double)den) kill |= 1u << j;
        }
        alive &= ~kill;
    }
    if (tid == 0) selcnt[g] = kout;
}

// ------ merge: per-image bitonic sort of all accepted, take top-K ----------
__global__ __launch_bounds__(256) void merge_kernel(
    const float* __restrict__ selbuf, const int* __restrict__ selcnt,
    float* __restrict__ out_dets, float* __restrict__ out_kl)
{
    int b = blockIdx.x, tid = threadIdx.x;
    __shared__ unsigned mkhi[MP], mklo[MP], mpay[MP];
    __shared__ int scnt[NCLS], soff[NCLS + 1];

    if (tid < NCLS) scnt[tid] = selcnt[b * NCLS + tid];
    __syncthreads();
    if (tid == 0) {
        int acc = 0;
        for (int c = 0; c < NCLS; ++c) { soff[c] = acc; acc += scnt[c]; }
        soff[NCLS] = acc;
    }
    __syncthreads();
    int tot = soff[NCLS];

    if (tot > MP) {
        // safety fallback: iterative 100-step merge on wave 0 (round-5 logic)
        if (tid >= 64) return;
        int lane = tid;
        int g0 = b * NCLS + lane;
        int g1 = (lane < NCLS - 64) ? g0 + 64 : -1;
        int c0 = scnt[lane];
        int c1 = (g1 >= 0) ? scnt[lane + 64] : 0;
        int p0 = 0, p1 = 0;
        unsigned long long k0c = 0, k1c = 0;
        if (p0 < c0) { const float* h = selbuf + ((size_t)g0 * NK) * 8;
            k0c = ((unsigned long long)__float_as_uint(h[0]) << 32) | (unsigned long long)(~(unsigned)h[6]); }
        if (g1 >= 0 && p1 < c1) { const float* h = selbuf + ((size_t)g1 * NK) * 8;
            k1c = ((unsigned long long)__float_as_uint(h[0]) << 32) | (unsigned long long)(~(unsigned)h[6]); }
        for (int k = 0; k < NK; ++k) {
            bool t1 = (k1c > k0c);
            unsigned long long bk = t1 ? k1c : k0c;
            int bslot = t1 ? (lane + 64) : lane;
            for (int o = 1; o < 64; o <<= 1) {
                unsigned long long k2 = __shfl_xor(bk, o);
                int b2 = __shfl_xor(bslot, o);
                if (k2 > bk) { bk = k2; bslot = b2; }
            }
            if (bk == 0ull) {
                for (int z = k * 5 + lane; z < NK * 5; z += 64)
                    out_dets[(size_t)b * NK * 5 + z] = 0.0f;
                for (int z = k + lane; z < NK; z += 64)
                    out_kl[(size_t)b * NK + z] = -1.0f;
                return;
            }
            int owner = bslot & 63;
            if (lane == owner) {
                bool isA = (bslot < 64);
                int gg = isA ? g0 : g1;
                int pp = isA ? p0 : p1;
                const float* e = selbuf + ((size_t)gg * NK + pp) * 8;
                size_t o = ((size_t)b * NK + k) * 5;
                out_dets[o + 0] = e[1]; out_dets[o + 1] = e[2];
                out_dets[o + 2] = e[3]; out_dets[o + 3] = e[4];
                out_dets[o + 4] = e[0];
                out_kl[(size_t)b * NK + k] = e[5];
                if (isA) {
                    p0++; k0c = 0;
                    if (p0 < c0) { const float* h = selbuf + ((size_t)g0 * NK + p0) * 8;
                        k0c = ((unsigned long long)__float_as_uint(h[0]) << 32) | (unsigned long long)(~(unsigned)h[6]); }
                } else {
                    p1++; k1c = 0;
                    if (p1 < c1) { const float* h = selbuf + ((size_t)g1 * NK + p1) * 8;
                        k1c = ((unsigned long long)__float_as_uint(h[0]) << 32) | (unsigned long long)(~(unsigned)h[6]); }
                }
            }
        }
        return;
    }

    // fast path: load all accepted entries, bitonic sort desc, write top-K
    for (int c = 0; c < NCLS; ++c) {
        int off = soff[c], cnt = scnt[c];
        for (int i = tid; i < cnt; i += 256) {
            const float* e = selbuf + ((size_t)(b * NCLS + c) * NK + i) * 8;
            mkhi[off + i] = __float_as_uint(e[0]);
            mklo[off + i] = ~((unsigned)e[6]);
            mpay[off + i] = (unsigned)(c * 128 + i);
        }
    }
    int P = 256; while (P < tot) P <<= 1;
    for (int i = tot + tid; i < P; i += 256) { mkhi[i] = 0u; mklo[i] = 0u; mpay[i] = 0u; }
    __syncthreads();
    for (int k = 2; k <= P; k <<= 1) {
        for (int j = k >> 1; j > 0; j >>= 1) {
            for (int t = tid; t < (P >> 1); t += 256) {
                int i = ((t & ~(j - 1)) << 1) | (t & (j - 1));
                int l = i | j;
                unsigned ah = mkhi[i], al = mklo[i], ch = mkhi[l], cl_ = mklo[l];
                bool alt = (ah < ch) || (ah == ch && al < cl_);
                bool agt = (ah > ch) || (ah == ch && al > cl_);
                bool sw = ((i & k) == 0) ? alt : agt;
                if (sw) {
                    mkhi[i] = ch; mklo[i] = cl_; mkhi[l] = ah; mklo[l] = al;
                    unsigned tp = mpay[i]; mpay[i] = mpay[l]; mpay[l] = tp;
                }
            }
            __syncthreads();
        }
    }
    int kc = (tot < NK) ? tot : NK;
    for (int k = tid; k < NK; k += 256) {
        size_t o = ((size_t)b * NK + k) * 5;
        if (k < kc) {
            unsigned pay = mpay[k];
            int c = (int)(pay >> 7), p = (int)(pay & 127);
            const float* e = selbuf + ((size_t)(b * NCLS + c) * NK + p) * 8;
            out_dets[o + 0] = e[1]; out_dets[o + 1] = e[2];
            out_dets[o + 2] = e[3]; out_dets[o + 3] = e[4];
            out_dets[o + 4] = e[0];
            out_kl[(size_t)b * NK + k] = e[5];
        } else {
            out_dets[o + 0] = 0.0f; out_dets[o + 1] = 0.0f;
            out_dets[o + 2] = 0.0f; out_dets[o + 3] = 0.0f;
            out_dets[o + 4] = 0.0f;
            out_kl[(size_t)b * NK + k] = -1.0f;
        }
    }
}

extern "C" void kernel_launch(void* const* d_in, const int* in_sizes, int n_in,
                              void* d_out, int out_size, void* d_ws, size_t ws_size,
                              hipStream_t stream) {
    const float* logits = (const float*)d_in[0];
    const float* reg    = (const float*)d_in[1];
    const float* props  = (const float*)d_in[2];
    const float* gtb    = (const float*)d_in[3];
    const int*   gtl    = (const int*)d_in[4];

    float* out          = (float*)d_out;
    float* out_dets     = out;                    // NB*NK*5 = 2000
    float* out_kl       = out + NB * NK * 5;      // NB*NK   = 400
    float* out_assigned = out_kl + NB * NK;       // NB*NN   = 24000
    float* out_matched  = out_assigned + NB * NN; // NB*NN   = 24000

    char* ws = (char*)d_ws;
    int*   cursors = (int*)(ws + 0);              // 360*32*4 = 46080 B
    int*   selcnt  = (int*)(ws + 49152);          // 1440 B
    float* selbuf  = (float*)(ws + 53248);        // 360*100*8*4 = 1152000 B
    size_t off_ent = 1205248;

    long avail = (long)ws_size - (long)off_ent;
    long per_slot = 6L * 4L * NBUC;               // 8640 B per slot index
    long slotsl = (avail > 0) ? avail / per_slot : 0;
    int slots = (int)((slotsl > SLOTS_MAX) ? SLOTS_MAX : (slotsl < 0 ? 0 : slotsl));

    size_t fsz = (size_t)NBUC * slots;            // floats per field
    float* e_sc = (float*)(ws + off_ent);
    float* e_x1 = e_sc + fsz;
    float* e_y1 = e_x1 + fsz;
    float* e_x2 = e_y1 + fsz;
    float* e_y2 = e_x2 + fsz;
    float* e_id = e_y2 + fsz;

    hipMemsetAsync(cursors, 0, NBUC * CUR_STRIDE * sizeof(int), stream);
    const int MATCH_BLOCKS = (NB * NN + 255) / 256;   // 94
    fused_kernel<<<RS_BLOCKS + MATCH_BLOCKS, 256, 0, stream>>>(
        logits, reg, props, gtb, gtl, out_assigned, out_matched,
        cursors, e_sc, e_x1, e_y1, e_x2, e_y2, e_id, slots);
    bucket_nms_kernel<<<NBUC, 64, 0, stream>>>(
        cursors, slots, e_sc, e_x1, e_y1, e_x2, e_y2, e_id, selbuf, selcnt);
    merge_kernel<<<NB, 256, 0, stream>>>(selbuf, selcnt, out_dets, out_kl);
}

// Round 7
// 160.866 us; speedup vs baseline: 36.4277x; 1.2125x over previous
//
#include <hip/hip_runtime.h>
#include <math.h>

#define NB 4
#define NN 6000
#define NC 91
#define NG 32
#define NK 100
#define NCLS (NC - 1)        /* 90 */
#define NBUC (NB * NCLS)     /* 360 */
#define SLOTS_MAX 2048
#define CUR_STRIDE 32        /* one cursor per 128B line (atomic padding) */
#define PMAX 512             /* fast-path bucket capacity */
#define MP 2048              /* merge fast-path capacity per image */
#define RS_BLOCKS 6000       /* 24000 rows / 4 waves per block */

#define SCORE_TH 0.05f
#define NMS_TH 0.5f
#define MATCH_TH 0.5f
#define MIN_SIZE 0.01f
#define BBOX_CLIP 4.135166556742356f  /* log(1000/16) */
/* fdiv_rn(inter,den) > 0.5f  <=>  (double)inter > C_SUP*(double)den  (exact) */
#define C_SUP 0.5000000298023223876953125

// ---------------- decode (identical op sequence to rounds 1-6) -------------
__device__ __forceinline__ bool decode_one(
    const float* __restrict__ reg, const float* __restrict__ props,
    float l, float m, float s0, int row, int c, float out[5])
{
    float score = __fdiv_rn(expf(__fsub_rn(l, m)), s0);

    const float4 p = *reinterpret_cast<const float4*>(props + (size_t)row * 4);
    float w  = __fsub_rn(p.z, p.x);
    float h  = __fsub_rn(p.w, p.y);
    float cx = __fadd_rn(p.x, __fmul_rn(0.5f, w));
    float cy = __fadd_rn(p.y, __fmul_rn(0.5f, h));

    const float4 r4 = *reinterpret_cast<const float4*>(
        reg + (size_t)row * (NC * 4) + (size_t)c * 4);
    float dx = __fdiv_rn(r4.x, 10.0f);
    float dy = __fdiv_rn(r4.y, 10.0f);
    float dw = fminf(__fdiv_rn(r4.z, 5.0f), BBOX_CLIP);
    float dh = fminf(__fdiv_rn(r4.w, 5.0f), BBOX_CLIP);

    float pcx = __fadd_rn(__fmul_rn(dx, w), cx);
    float pcy = __fadd_rn(__fmul_rn(dy, h), cy);
    float pw  = __fmul_rn(expf(dw), w);
    float ph  = __fmul_rn(expf(dh), h);

    float x1 = __fsub_rn(pcx, __fmul_rn(0.5f, pw));
    float y1 = __fsub_rn(pcy, __fmul_rn(0.5f, ph));
    float x2 = __fadd_rn(pcx, __fmul_rn(0.5f, pw));
    float y2 = __fadd_rn(pcy, __fmul_rn(0.5f, ph));
    x1 = fminf(fmaxf(x1, 0.0f), 800.0f);
    y1 = fminf(fmaxf(y1, 0.0f), 800.0f);
    x2 = fminf(fmaxf(x2, 0.0f), 800.0f);
    y2 = fminf(fmaxf(y2, 0.0f), 800.0f);

    out[0] = score; out[1] = x1; out[2] = y1; out[3] = x2; out[4] = y2;
    float ws_ = __fsub_rn(x2, x1);
    float hs_ = __fsub_rn(y2, y1);
    return (score > SCORE_TH) && (ws_ >= MIN_SIZE) && (hs_ >= MIN_SIZE);
}

// ---- fused: softmax stats + in-register prefilter + fill  |  matcher ------
__global__ __launch_bounds__(256) void fused_kernel(
    const float* __restrict__ logits, const float* __restrict__ reg,
    const float* __restrict__ props, const float* __restrict__ gtb,
    const int* __restrict__ gtl,
    float* __restrict__ out_assigned, float* __restrict__ out_matched,
    int* __restrict__ cursors,
    float* __restrict__ e_sc, float* __restrict__ e_x1,
    float* __restrict__ e_y1, float* __restrict__ e_x2,
    float* __restrict__ e_y2, float* __restrict__ e_id, int slots)
{
    int bid = blockIdx.x;
    if (bid < RS_BLOCKS) {
        int wid = threadIdx.x >> 6, lane = threadIdx.x & 63;
        int row = bid * 4 + wid;                 // [0, 24000)
        const float* rp = logits + (size_t)row * NC;
        float l0 = rp[lane];
        float l1 = (lane < NC - 64) ? rp[64 + lane] : -INFINITY;
        // max: same sequential-then-tree order as previous rowstats
        float m = fmaxf(fmaxf(-INFINITY, l0), l1);
        for (int o = 32; o; o >>= 1) m = fmaxf(m, __shfl_down(m, o));
        m = __shfl(m, 0);
        float s = __fadd_rn(__fadd_rn(0.0f, expf(__fsub_rn(l0, m))),
                            expf(__fsub_rn(l1, m)));   // exp(-inf)=0 exact
        for (int o = 32; o; o >>= 1) s = __fadd_rn(s, __shfl_down(s, o));
        float s0 = __shfl(s, 0);
        // conservative prefilter: score>0.05 => l > m + log(0.04*s)
        float thr = __fadd_rn(m, logf(__fmul_rn(0.04f, s0)));

        int b = row / NN;
        int nprop = row - b * NN;

        // candidate 1: class c = lane (skip background c==0)
        if (lane >= 1 && l0 > thr) {
            float o[5];
            if (decode_one(reg, props, l0, m, s0, row, lane, o)) {
                int c = lane;
                int g = b * NCLS + (c - 1);
                int pos = atomicAdd(&cursors[g * CUR_STRIDE], 1);
                if (pos < slots) {
                    size_t idx = (size_t)g * slots + pos;
                    e_sc[idx] = o[0]; e_x1[idx] = o[1]; e_y1[idx] = o[2];
                    e_x2[idx] = o[3]; e_y2[idx] = o[4];
                    e_id[idx] = (float)(nprop * NCLS + (c - 1));
                }
            }
        }
        // candidate 2: class c = lane + 64 (lanes 0..26)
        if (lane < NC - 64 && l1 > thr) {
            float o[5];
            int c = lane + 64;
            if (decode_one(reg, props, l1, m, s0, row, c, o)) {
                int g = b * NCLS + (c - 1);
                int pos = atomicAdd(&cursors[g * CUR_STRIDE], 1);
                if (pos < slots) {
                    size_t idx = (size_t)g * slots + pos;
                    e_sc[idx] = o[0]; e_x1[idx] = o[1]; e_y1[idx] = o[2];
                    e_x2[idx] = o[3]; e_y2[idx] = o[4];
                    e_id[idx] = (float)(nprop * NCLS + (c - 1));
                }
            }
        }
    } else {
        // ---- matcher blocks ----
        int t = (bid - RS_BLOCKS) * 256 + threadIdx.x;
        if (t >= NB * NN) return;
        int b = t / NN;
        const float4 p = *reinterpret_cast<const float4*>(props + (size_t)t * 4);
        float parea = __fmul_rn(__fsub_rn(p.z, p.x), __fsub_rn(p.w, p.y));
        float best = -1.0f; int bi = -1;
        for (int g = 0; g < NG; ++g) {
            const float4 q = *reinterpret_cast<const float4*>(gtb + ((size_t)b * NG + g) * 4);
            float garea = __fmul_rn(__fsub_rn(q.z, q.x), __fsub_rn(q.w, q.y));
            float ltx = fmaxf(q.x, p.x), lty = fmaxf(q.y, p.y);
            float rbx = fminf(q.z, p.z), rby = fminf(q.w, p.w);
            float wx = fmaxf(__fsub_rn(rbx, ltx), 0.0f);
            float wy = fmaxf(__fsub_rn(rby, lty), 0.0f);
            float inter = __fmul_rn(wx, wy);
            float iou = __fdiv_rn(inter, __fsub_rn(__fadd_rn(garea, parea), inter));
            if (iou > best) { best = iou; bi = g; }
        }
        int matched = (best >= MATCH_TH) ? bi : -1;
        int assigned = (matched >= 0) ? gtl[b * NG + matched] : 0;
        out_matched[t]  = (float)matched;
        out_assigned[t] = (float)assigned;
    }
}

// ---------------- wave-serial fallback for n > PMAX (never expected) -------
__device__ void nms_glb(int g, int n, float* __restrict__ SC,
                        const float* __restrict__ X1, const float* __restrict__ Y1,
                        const float* __restrict__ X2, const float* __restrict__ Y2,
                        const float* __restrict__ ID, float tb, float cls,
                        float* __restrict__ selbuf, int* __restrict__ selcnt)
{
    int lane = threadIdx.x;
    int kout = 0;
    for (int k = 0; k < NK; ++k) {
        float bv = -INFINITY, boi = INFINITY; int bi = -1;
        for (int i = lane; i < n; i += 64) {
            float v = SC[i], oi = ID[i];
            if (v > bv || (v == bv && oi < boi)) { bv = v; boi = oi; bi = i; }
        }
        int wl = lane;
        for (int o = 1; o < 64; o <<= 1) {
            float v2 = __shfl_xor(bv, o); float o2 = __shfl_xor(boi, o);
            int l2 = __shfl_xor(wl, o);
            bool bt = (v2 > bv) || (v2 == bv && o2 < boi);
            bv = bt ? v2 : bv; boi = bt ? o2 : boi; wl = bt ? l2 : wl;
        }
        if (bv == -INFINITY) break;
        int wi = __shfl(bi, wl);
        float sx1 = X1[wi], sy1 = Y1[wi], sx2 = X2[wi], sy2 = Y2[wi];
        if (lane == wl) {
            float* so = selbuf + ((size_t)g * NK + k) * 8;
            so[0] = bv; so[1] = sx1; so[2] = sy1; so[3] = sx2; so[4] = sy2;
            so[5] = cls; so[6] = boi; so[7] = 0.0f;
        }
        float bx1 = __fadd_rn(sx1, tb), by1 = __fadd_rn(sy1, tb);
        float bx2 = __fadd_rn(sx2, tb), by2 = __fadd_rn(sy2, tb);
        float sar = __fmul_rn(__fsub_rn(bx2, bx1), __fsub_rn(by2, by1));
        for (int i = lane; i < n; i += 64) {
            float v = SC[i];
            if (v == -INFINITY) continue;
            float ox1 = __fadd_rn(X1[i], tb), oy1 = __fadd_rn(Y1[i], tb);
            float ox2 = __fadd_rn(X2[i], tb), oy2 = __fadd_rn(Y2[i], tb);
            float oar = __fmul_rn(__fsub_rn(ox2, ox1), __fsub_rn(oy2, oy1));
            float ltx = fmaxf(ox1, bx1), lty = fmaxf(oy1, by1);
            float rbx = fminf(ox2, bx2), rby = fminf(oy2, by2);
            float wx = fmaxf(__fsub_rn(rbx, ltx), 0.0f);
            float wy = fmaxf(__fsub_rn(rby, lty), 0.0f);
            float inter = __fmul_rn(wx, wy);
            float den = __fsub_rn(__fadd_rn(oar, sar), inter);
            if ((double)inter > C_SUP * (double)den) SC[i] = -INFINITY;
        }
        kout = k + 1;
    }
    if (lane == 0) selcnt[g] = kout;
}

// -------- sort + LDS-staged sorted sweep (no global ops in loop) -----------
__global__ __launch_bounds__(64) void bucket_nms_kernel(
    const int* __restrict__ cursors, int slots,
    float* __restrict__ e_sc, const float* __restrict__ e_x1,
    const float* __restrict__ e_y1, const float* __restrict__ e_x2,
    const float* __restrict__ e_y2, const float* __restrict__ e_id,
    float* __restrict__ selbuf, int* __restrict__ selcnt)
{
    int g = blockIdx.x;
    int n = cursors[g * CUR_STRIDE]; if (n > slots) n = slots;
    int tid = threadIdx.x;
    if (n == 0) { if (tid == 0) selcnt[g] = 0; return; }
    size_t base = (size_t)g * slots;
    float cls = (float)(g % NCLS + 1);
    float tb = __fmul_rn(cls, 801.0f);

    if (n > PMAX) {
        nms_glb(g, n, e_sc + base, e_x1 + base, e_y1 + base,
                e_x2 + base, e_y2 + base, e_id + base, tb, cls, selbuf, selcnt);
        return;
    }

    __shared__ unsigned skhi[PMAX], sklo[PMAX], sperm[PMAX];
    __shared__ float4 sbox[PMAX];
    __shared__ float soar[PMAX];
    __shared__ int acc[NK];

    int P = 64; while (P < n) P <<= 1;

    for (int i = tid; i < P; i += 64) {
        if (i < n) {
            skhi[i] = __float_as_uint(e_sc[base + i]);
            sklo[i] = ~((unsigned)e_id[base + i]);   // u64 max == (score desc, idx asc)
        } else { skhi[i] = 0u; sklo[i] = 0u; }
        sperm[i] = i;
    }
    __syncthreads();
    // bitonic sort desc on (skhi,sklo); u32 arrays => <=2-way bank alias (free)
    for (int k = 2; k <= P; k <<= 1) {
        for (int j = k >> 1; j > 0; j >>= 1) {
            for (int t = tid; t < (P >> 1); t += 64) {
                int i = ((t & ~(j - 1)) << 1) | (t & (j - 1));
                int l = i | j;
                unsigned ah = skhi[i], al = sklo[i], ch = skhi[l], cl_ = sklo[l];
                bool alt = (ah < ch) || (ah == ch && al < cl_);
                bool agt = (ah > ch) || (ah == ch && al > cl_);
                bool sw = ((i & k) == 0) ? alt : agt;
                if (sw) {
                    skhi[i] = ch; sklo[i] = cl_; skhi[l] = ah; sklo[l] = al;
                    unsigned tp = sperm[i]; sperm[i] = sperm[l]; sperm[l] = tp;
                }
            }
            __syncthreads();
        }
    }
    // phase 2: gather sorted boxes -> registers AND LDS (offset coords, areas)
    float ox1[8], oy1[8], ox2[8], oy2[8], oar[8];
    unsigned alive = 0;
#pragma unroll
    for (int j = 0; j < 8; ++j) {
        int sidx = tid * 8 + j;
        if (sidx < n) {
            int sl = (int)sperm[sidx];
            float a  = __fadd_rn(e_x1[base + sl], tb);
            float b_ = __fadd_rn(e_y1[base + sl], tb);
            float c_ = __fadd_rn(e_x2[base + sl], tb);
            float d_ = __fadd_rn(e_y2[base + sl], tb);
            float ar = __fmul_rn(__fsub_rn(c_, a), __fsub_rn(d_, b_));
            ox1[j] = a; oy1[j] = b_; ox2[j] = c_; oy2[j] = d_; oar[j] = ar;
            sbox[sidx] = make_float4(a, b_, c_, d_);
            soar[sidx] = ar;
            alive |= 1u << j;
        } else {
            ox1[j] = 0.f; oy1[j] = 0.f; ox2[j] = 0.f; oy2[j] = 0.f; oar[j] = 0.f;
        }
    }
    __syncthreads();

    // phase 3: sweep — registers + scalar readlane + LDS broadcast only
    int kout = 0;
    while (kout < NK) {
        unsigned long long bal = __ballot(alive != 0u);
        if (!bal) break;
        int fl = (int)__ffsll(bal) - 1;                               // uniform
        unsigned am = (unsigned)__builtin_amdgcn_readlane((int)alive, fl);
        int js = __ffs(am) - 1;                                       // uniform
        int cand = fl * 8 + js;                                       // uniform
        float4 bb = sbox[cand];          // same-address broadcast (free)
        float bar = soar[cand];
        if (tid == 0) acc[kout] = cand;  // fire-and-forget ds_write
        kout++;
        unsigned kill = 0;
#pragma unroll
        for (int j = 0; j < 8; ++j) {
            float ltx = fmaxf(ox1[j], bb.x), lty = fmaxf(oy1[j], bb.y);
            float rbx = fminf(ox2[j], bb.z), rby = fminf(oy2[j], bb.w);
            float wx = fmaxf(__fsub_rn(rbx, ltx), 0.0f);
            float wy = fmaxf(__fsub_rn(rby, lty), 0.0f);
            float inter = __fmul_rn(wx, wy);
            float den = __fsub_rn(__fadd_rn(oar[j], bar), inter);
            if ((double)inter > C_SUP * (double)den) kill |= 1u << j;
        }
        alive &= ~kill;
    }
    __syncthreads();
    if (tid == 0) selcnt[g] = kout;

    // phase 4: parallel output write (sorted desc by construction)
    for (int k = tid; k < kout; k += 64) {
        int cand = acc[k];
        int sl = (int)sperm[cand];
        float* so = selbuf + ((size_t)g * NK + k) * 8;
        so[0] = __uint_as_float(skhi[cand]);
        so[1] = e_x1[base + sl]; so[2] = e_y1[base + sl];
        so[3] = e_x2[base + sl]; so[4] = e_y2[base + sl];
        so[5] = cls; so[6] = (float)(~sklo[cand]); so[7] = 0.0f;
    }
}

// ------ merge: per-image bitonic sort of all accepted, take top-K ----------
__global__ __launch_bounds__(256) void merge_kernel(
    const float* __restrict__ selbuf, const int* __restrict__ selcnt,
    float* __restrict__ out_dets, float* __restrict__ out_kl)
{
    int b = blockIdx.x, tid = threadIdx.x;
    __shared__ unsigned mkhi[MP], mklo[MP], mpay[MP];
    __shared__ int scnt[NCLS], soff[NCLS + 1];

    if (tid < NCLS) scnt[tid] = selcnt[b * NCLS + tid];
    __syncthreads();
    if (tid == 0) {
        int acc = 0;
        for (int c = 0; c < NCLS; ++c) { soff[c] = acc; acc += scnt[c]; }
        soff[NCLS] = acc;
    }
    __syncthreads();
    int tot = soff[NCLS];

    if (tot > MP) {
        // safety fallback: iterative 100-step merge on wave 0
        if (tid >= 64) return;
        int lane = tid;
        int g0 = b * NCLS + lane;
        int g1 = (lane < NCLS - 64) ? g0 + 64 : -1;
        int c0 = scnt[lane];
        int c1 = (g1 >= 0) ? scnt[lane + 64] : 0;
        int p0 = 0, p1 = 0;
        unsigned long long k0c = 0, k1c = 0;
        if (p0 < c0) { const float* h = selbuf + ((size_t)g0 * NK) * 8;
            k0c = ((unsigned long long)__float_as_uint(h[0]) << 32) | (unsigned long long)(~(unsigned)h[6]); }
        if (g1 >= 0 && p1 < c1) { const float* h = selbuf + ((size_t)g1 * NK) * 8;
            k1c = ((unsigned long long)__float_as_uint(h[0]) << 32) | (unsigned long long)(~(unsigned)h[6]); }
        for (int k = 0; k < NK; ++k) {
            bool t1 = (k1c > k0c);
            unsigned long long bk = t1 ? k1c : k0c;
            int bslot = t1 ? (lane + 64) : lane;
            for (int o = 1; o < 64; o <<= 1) {
                unsigned long long k2 = __shfl_xor(bk, o);
                int b2 = __shfl_xor(bslot, o);
                if (k2 > bk) { bk = k2; bslot = b2; }
            }
            if (bk == 0ull) {
                for (int z = k * 5 + lane; z < NK * 5; z += 64)
                    out_dets[(size_t)b * NK * 5 + z] = 0.0f;
                for (int z = k + lane; z < NK; z += 64)
                    out_kl[(size_t)b * NK + z] = -1.0f;
                return;
            }
            int owner = bslot & 63;
            if (lane == owner) {
                bool isA = (bslot < 64);
                int gg = isA ? g0 : g1;
                int pp = isA ? p0 : p1;
                const float* e = selbuf + ((size_t)gg * NK + pp) * 8;
                size_t o = ((size_t)b * NK + k) * 5;
                out_dets[o + 0] = e[1]; out_dets[o + 1] = e[2];
                out_dets[o + 2] = e[3]; out_dets[o + 3] = e[4];
                out_dets[o + 4] = e[0];
                out_kl[(size_t)b * NK + k] = e[5];
                if (isA) {
                    p0++; k0c = 0;
                    if (p0 < c0) { const float* h = selbuf + ((size_t)g0 * NK + p0) * 8;
                        k0c = ((unsigned long long)__float_as_uint(h[0]) << 32) | (unsigned long long)(~(unsigned)h[6]); }
                } else {
                    p1++; k1c = 0;
                    if (p1 < c1) { const float* h = selbuf + ((size_t)g1 * NK + p1) * 8;
                        k1c = ((unsigned long long)__float_as_uint(h[0]) << 32) | (unsigned long long)(~(unsigned)h[6]); }
                }
            }
        }
        return;
    }

    // fast path: load all accepted entries, bitonic sort desc, write top-K
    for (int c = 0; c < NCLS; ++c) {
        int off = soff[c], cnt = scnt[c];
        for (int i = tid; i < cnt; i += 256) {
            const float* e = selbuf + ((size_t)(b * NCLS + c) * NK + i) * 8;
            mkhi[off + i] = __float_as_uint(e[0]);
            mklo[off + i] = ~((unsigned)e[6]);
            mpay[off + i] = (unsigned)(c * 128 + i);
        }
    }
    int P = 256; while (P < tot) P <<= 1;
    for (int i = tot + tid; i < P; i += 256) { mkhi[i] = 0u; mklo[i] = 0u; mpay[i] = 0u; }
    __syncthreads();
    for (int k = 2; k <= P; k <<= 1) {
        for (int j = k >> 1; j > 0; j >>= 1) {
            for (int t = tid; t < (P >> 1); t += 256) {
                int i = ((t & ~(j - 1)) << 1) | (t & (j - 1));
                int l = i | j;
                unsigned ah = mkhi[i], al = mklo[i], ch = mkhi[l], cl_ = mklo[l];
                bool alt = (ah < ch) || (ah == ch && al < cl_);
                bool agt = (ah > ch) || (ah == ch && al > cl_);
                bool sw = ((i & k) == 0) ? alt : agt;
                if (sw) {
                    mkhi[i] = ch; mklo[i] = cl_; mkhi[l] = ah; mklo[l] = al;
                    unsigned tp = mpay[i]; mpay[i] = mpay[l]; mpay[l] = tp;
                }
            }
            __syncthreads();
        }
    }
    int kc = (tot < NK) ? tot : NK;
    for (int k = tid; k < NK; k += 256) {
        size_t o = ((size_t)b * NK + k) * 5;
        if (k < kc) {
            unsigned pay = mpay[k];
            int c = (int)(pay >> 7), p = (int)(pay & 127);
            const float* e = selbuf + ((size_t)(b * NCLS + c) * NK + p) * 8;
            out_dets[o + 0] = e[1]; out_dets[o + 1] = e[2];
            out_dets[o + 2] = e[3]; out_dets[o + 3] = e[4];
            out_dets[o + 4] = e[0];
            out_kl[(size_t)b * NK + k] = e[5];
        } else {
            out_dets[o + 0] = 0.0f; out_dets[o + 1] = 0.0f;
            out_dets[o + 2] = 0.0f; out_dets[o + 3] = 0.0f;
            out_dets[o + 4] = 0.0f;
            out_kl[(size_t)b * NK + k] = -1.0f;
        }
    }
}

extern "C" void kernel_launch(void* const* d_in, const int* in_sizes, int n_in,
                              void* d_out, int out_size, void* d_ws, size_t ws_size,
                              hipStream_t stream) {
    const float* logits = (const float*)d_in[0];
    const float* reg    = (const float*)d_in[1];
    const float* props  = (const float*)d_in[2];
    const float* gtb    = (const float*)d_in[3];
    const int*   gtl    = (const int*)d_in[4];

    float* out          = (float*)d_out;
    float* out_dets     = out;                    // NB*NK*5 = 2000
    float* out_kl       = out + NB * NK * 5;      // NB*NK   = 400
    float* out_assigned = out_kl + NB * NK;       // NB*NN   = 24000
    float* out_matched  = out_assigned + NB * NN; // NB*NN   = 24000

    char* ws = (char*)d_ws;
    int*   cursors = (int*)(ws + 0);              // 360*32*4 = 46080 B
    int*   selcnt  = (int*)(ws + 49152);          // 1440 B
    float* selbuf  = (float*)(ws + 53248);        // 360*100*8*4 = 1152000 B
    size_t off_ent = 1205248;

    long avail = (long)ws_size - (long)off_ent;
    long per_slot = 6L * 4L * NBUC;               // 8640 B per slot index
    long slotsl = (avail > 0) ? avail / per_slot : 0;
    int slots = (int)((slotsl > SLOTS_MAX) ? SLOTS_MAX : (slotsl < 0 ? 0 : slotsl));

    size_t fsz = (size_t)NBUC * slots;            // floats per field
    float* e_sc = (float*)(ws + off_ent);
    float* e_x1 = e_sc + fsz;
    float* e_y1 = e_x1 + fsz;
    float* e_x2 = e_y1 + fsz;
    float* e_y2 = e_x2 + fsz;
    float* e_id = e_y2 + fsz;

    hipMemsetAsync(cursors, 0, NBUC * CUR_STRIDE * sizeof(int), stream);
    const int MATCH_BLOCKS = (NB * NN + 255) / 256;   // 94
    fused_kernel<<<RS_BLOCKS + MATCH_BLOCKS, 256, 0, stream>>>(
        logits, reg, props, gtb, gtl, out_assigned, out_matched,
        cursors, e_sc, e_x1, e_y1, e_x2, e_y2, e_id, slots);
    bucket_nms_kernel<<<NBUC, 64, 0, stream>>>(
        cursors, slots, e_sc, e_x1, e_y1, e_x2, e_y2, e_id, selbuf, selcnt);
    merge_kernel<<<NB, 256, 0, stream>>>(selbuf, selcnt, out_dets, out_kl);
}

// Round 8
// 151.515 us; speedup vs baseline: 38.6759x; 1.0617x over previous
//
#include <hip/hip_runtime.h>
#include <math.h>

#define NB 4
#define NN 6000
#define NC 91
#define NG 32
#define NK 100
#define NCLS (NC - 1)        /* 90 */
#define NBUC (NB * NCLS)     /* 360 */
#define SLOTS_MAX 2048
#define CUR_STRIDE 32        /* one cursor per 128B line (atomic padding) */
#define PMAX 512             /* fast-path bucket capacity */
#define MP 2048              /* merge fast-path capacity per image */
#define RS_BLOCKS 6000       /* 24000 rows / 4 waves per block */

#define SCORE_TH 0.05f
#define NMS_TH 0.5f
#define MATCH_TH 0.5f
#define MIN_SIZE 0.01f
#define BBOX_CLIP 4.135166556742356f  /* log(1000/16) */
/* fdiv_rn(inter,den) > 0.5f  <=>  (double)inter > C_SUP*(double)den  (exact) */
#define C_SUP 0.5000000298023223876953125

// ---------------- decode (identical op sequence to rounds 1-7) -------------
__device__ __forceinline__ bool decode_one(
    const float* __restrict__ reg, const float* __restrict__ props,
    float l, float m, float s0, int row, int c, float out[5])
{
    float score = __fdiv_rn(expf(__fsub_rn(l, m)), s0);

    const float4 p = *reinterpret_cast<const float4*>(props + (size_t)row * 4);
    float w  = __fsub_rn(p.z, p.x);
    float h  = __fsub_rn(p.w, p.y);
    float cx = __fadd_rn(p.x, __fmul_rn(0.5f, w));
    float cy = __fadd_rn(p.y, __fmul_rn(0.5f, h));

    const float4 r4 = *reinterpret_cast<const float4*>(
        reg + (size_t)row * (NC * 4) + (size_t)c * 4);
    float dx = __fdiv_rn(r4.x, 10.0f);
    float dy = __fdiv_rn(r4.y, 10.0f);
    float dw = fminf(__fdiv_rn(r4.z, 5.0f), BBOX_CLIP);
    float dh = fminf(__fdiv_rn(r4.w, 5.0f), BBOX_CLIP);

    float pcx = __fadd_rn(__fmul_rn(dx, w), cx);
    float pcy = __fadd_rn(__fmul_rn(dy, h), cy);
    float pw  = __fmul_rn(expf(dw), w);
    float ph  = __fmul_rn(expf(dh), h);

    float x1 = __fsub_rn(pcx, __fmul_rn(0.5f, pw));
    float y1 = __fsub_rn(pcy, __fmul_rn(0.5f, ph));
    float x2 = __fadd_rn(pcx, __fmul_rn(0.5f, pw));
    float y2 = __fadd_rn(pcy, __fmul_rn(0.5f, ph));
    x1 = fminf(fmaxf(x1, 0.0f), 800.0f);
    y1 = fminf(fmaxf(y1, 0.0f), 800.0f);
    x2 = fminf(fmaxf(x2, 0.0f), 800.0f);
    y2 = fminf(fmaxf(y2, 0.0f), 800.0f);

    out[0] = score; out[1] = x1; out[2] = y1; out[3] = x2; out[4] = y2;
    float ws_ = __fsub_rn(x2, x1);
    float hs_ = __fsub_rn(y2, y1);
    return (score > SCORE_TH) && (ws_ >= MIN_SIZE) && (hs_ >= MIN_SIZE);
}

// ---- fused: softmax stats + in-register prefilter + fill  |  matcher ------
__global__ __launch_bounds__(256) void fused_kernel(
    const float* __restrict__ logits, const float* __restrict__ reg,
    const float* __restrict__ props, const float* __restrict__ gtb,
    const int* __restrict__ gtl,
    float* __restrict__ out_assigned, float* __restrict__ out_matched,
    int* __restrict__ cursors,
    float* __restrict__ e_sc, float* __restrict__ e_x1,
    float* __restrict__ e_y1, float* __restrict__ e_x2,
    float* __restrict__ e_y2, float* __restrict__ e_id, int slots)
{
    int bid = blockIdx.x;
    if (bid < RS_BLOCKS) {
        int wid = threadIdx.x >> 6, lane = threadIdx.x & 63;
        int row = bid * 4 + wid;                 // [0, 24000)
        const float* rp = logits + (size_t)row * NC;
        float l0 = rp[lane];
        float l1 = (lane < NC - 64) ? rp[64 + lane] : -INFINITY;
        float m = fmaxf(fmaxf(-INFINITY, l0), l1);
        for (int o = 32; o; o >>= 1) m = fmaxf(m, __shfl_down(m, o));
        m = __shfl(m, 0);
        float s = __fadd_rn(__fadd_rn(0.0f, expf(__fsub_rn(l0, m))),
                            expf(__fsub_rn(l1, m)));   // exp(-inf)=0 exact
        for (int o = 32; o; o >>= 1) s = __fadd_rn(s, __shfl_down(s, o));
        float s0 = __shfl(s, 0);
        // conservative prefilter: score>0.05 => l > m + log(0.04*s)
        float thr = __fadd_rn(m, logf(__fmul_rn(0.04f, s0)));

        int b = row / NN;
        int nprop = row - b * NN;

        if (lane >= 1 && l0 > thr) {
            float o[5];
            if (decode_one(reg, props, l0, m, s0, row, lane, o)) {
                int c = lane;
                int g = b * NCLS + (c - 1);
                int pos = atomicAdd(&cursors[g * CUR_STRIDE], 1);
                if (pos < slots) {
                    size_t idx = (size_t)g * slots + pos;
                    e_sc[idx] = o[0]; e_x1[idx] = o[1]; e_y1[idx] = o[2];
                    e_x2[idx] = o[3]; e_y2[idx] = o[4];
                    e_id[idx] = (float)(nprop * NCLS + (c - 1));
                }
            }
        }
        if (lane < NC - 64 && l1 > thr) {
            float o[5];
            int c = lane + 64;
            if (decode_one(reg, props, l1, m, s0, row, c, o)) {
                int g = b * NCLS + (c - 1);
                int pos = atomicAdd(&cursors[g * CUR_STRIDE], 1);
                if (pos < slots) {
                    size_t idx = (size_t)g * slots + pos;
                    e_sc[idx] = o[0]; e_x1[idx] = o[1]; e_y1[idx] = o[2];
                    e_x2[idx] = o[3]; e_y2[idx] = o[4];
                    e_id[idx] = (float)(nprop * NCLS + (c - 1));
                }
            }
        }
    } else {
        // ---- matcher blocks ----
        int t = (bid - RS_BLOCKS) * 256 + threadIdx.x;
        if (t >= NB * NN) return;
        int b = t / NN;
        const float4 p = *reinterpret_cast<const float4*>(props + (size_t)t * 4);
        float parea = __fmul_rn(__fsub_rn(p.z, p.x), __fsub_rn(p.w, p.y));
        float best = -1.0f; int bi = -1;
        for (int g = 0; g < NG; ++g) {
            const float4 q = *reinterpret_cast<const float4*>(gtb + ((size_t)b * NG + g) * 4);
            float garea = __fmul_rn(__fsub_rn(q.z, q.x), __fsub_rn(q.w, q.y));
            float ltx = fmaxf(q.x, p.x), lty = fmaxf(q.y, p.y);
            float rbx = fminf(q.z, p.z), rby = fminf(q.w, p.w);
            float wx = fmaxf(__fsub_rn(rbx, ltx), 0.0f);
            float wy = fmaxf(__fsub_rn(rby, lty), 0.0f);
            float inter = __fmul_rn(wx, wy);
            float iou = __fdiv_rn(inter, __fsub_rn(__fadd_rn(garea, parea), inter));
            if (iou > best) { best = iou; bi = g; }
        }
        int matched = (best >= MATCH_TH) ? bi : -1;
        int assigned = (matched >= 0) ? gtl[b * NG + matched] : 0;
        out_matched[t]  = (float)matched;
        out_assigned[t] = (float)assigned;
    }
}

// ---------------- wave-serial fallback for n > PMAX (never expected) -------
__device__ void nms_glb(int g, int n, float* __restrict__ SC,
                        const float* __restrict__ X1, const float* __restrict__ Y1,
                        const float* __restrict__ X2, const float* __restrict__ Y2,
                        const float* __restrict__ ID, float tb, float cls,
                        float* __restrict__ selbuf, int* __restrict__ selcnt)
{
    int lane = threadIdx.x;
    int kout = 0;
    for (int k = 0; k < NK; ++k) {
        float bv = -INFINITY, boi = INFINITY; int bi = -1;
        for (int i = lane; i < n; i += 64) {
            float v = SC[i], oi = ID[i];
            if (v > bv || (v == bv && oi < boi)) { bv = v; boi = oi; bi = i; }
        }
        int wl = lane;
        for (int o = 1; o < 64; o <<= 1) {
            float v2 = __shfl_xor(bv, o); float o2 = __shfl_xor(boi, o);
            int l2 = __shfl_xor(wl, o);
            bool bt = (v2 > bv) || (v2 == bv && o2 < boi);
            bv = bt ? v2 : bv; boi = bt ? o2 : boi; wl = bt ? l2 : wl;
        }
        if (bv == -INFINITY) break;
        int wi = __shfl(bi, wl);
        float sx1 = X1[wi], sy1 = Y1[wi], sx2 = X2[wi], sy2 = Y2[wi];
        if (lane == wl) {
            float* so = selbuf + ((size_t)g * NK + k) * 8;
            so[0] = bv; so[1] = sx1; so[2] = sy1; so[3] = sx2; so[4] = sy2;
            so[5] = cls; so[6] = boi; so[7] = 0.0f;
        }
        float bx1 = __fadd_rn(sx1, tb), by1 = __fadd_rn(sy1, tb);
        float bx2 = __fadd_rn(sx2, tb), by2 = __fadd_rn(sy2, tb);
        float sar = __fmul_rn(__fsub_rn(bx2, bx1), __fsub_rn(by2, by1));
        for (int i = lane; i < n; i += 64) {
            float v = SC[i];
            if (v == -INFINITY) continue;
            float ox1 = __fadd_rn(X1[i], tb), oy1 = __fadd_rn(Y1[i], tb);
            float ox2 = __fadd_rn(X2[i], tb), oy2 = __fadd_rn(Y2[i], tb);
            float oar = __fmul_rn(__fsub_rn(ox2, ox1), __fsub_rn(oy2, oy1));
            float ltx = fmaxf(ox1, bx1), lty = fmaxf(oy1, by1);
            float rbx = fminf(ox2, bx2), rby = fminf(oy2, by2);
            float wx = fmaxf(__fsub_rn(rbx, ltx), 0.0f);
            float wy = fmaxf(__fsub_rn(rby, lty), 0.0f);
            float inter = __fmul_rn(wx, wy);
            float den = __fsub_rn(__fadd_rn(oar, sar), inter);
            if ((double)inter > C_SUP * (double)den) SC[i] = -INFINITY;
        }
        kout = k + 1;
    }
    if (lane == 0) selcnt[g] = kout;
}

__device__ __forceinline__ float sel8(const float a[8], int j) {
    float r = a[0];
#pragma unroll
    for (int i = 1; i < 8; ++i) r = (j == i) ? a[i] : r;
    return r;
}
__device__ __forceinline__ float rdlane(float v, int l) {
    return __uint_as_float(
        (unsigned)__builtin_amdgcn_readlane((int)__float_as_uint(v), l));
}

// ---- 256-thr sort + LDS stage + register/readlane sweep (wave 0) ----------
__global__ __launch_bounds__(256) void bucket_nms_kernel(
    const int* __restrict__ cursors, int slots,
    float* __restrict__ e_sc, const float* __restrict__ e_x1,
    const float* __restrict__ e_y1, const float* __restrict__ e_x2,
    const float* __restrict__ e_y2, const float* __restrict__ e_id,
    float* __restrict__ selbuf, int* __restrict__ selcnt)
{
    int g = blockIdx.x;
    int n = cursors[g * CUR_STRIDE]; if (n > slots) n = slots;
    int tid = threadIdx.x;
    if (n == 0) { if (tid == 0) selcnt[g] = 0; return; }
    size_t base = (size_t)g * slots;
    float cls = (float)(g % NCLS + 1);
    float tb = __fmul_rn(cls, 801.0f);

    if (n > PMAX) {
        if (tid < 64)
            nms_glb(g, n, e_sc + base, e_x1 + base, e_y1 + base,
                    e_x2 + base, e_y2 + base, e_id + base, tb, cls,
                    selbuf, selcnt);
        return;
    }

    __shared__ unsigned skhi[PMAX], sklo[PMAX];
    __shared__ int sperm[PMAX];
    __shared__ float sx1[PMAX], sy1[PMAX], sx2[PMAX], sy2[PMAX];
    __shared__ int acc[NK];
    __shared__ int s_kout;

    int P = 64; while (P < n) P <<= 1;

    for (int i = tid; i < P; i += 256) {
        if (i < n) {
            skhi[i] = __float_as_uint(e_sc[base + i]);
            sklo[i] = ~((unsigned)e_id[base + i]);   // u64 max == (score desc, idx asc)
        } else { skhi[i] = 0u; sklo[i] = 0u; }
        sperm[i] = i;
    }
    __syncthreads();
    // bitonic sort desc on (skhi,sklo); 256 threads -> 1 iter/stage at P=512
    for (int k = 2; k <= P; k <<= 1) {
        for (int j = k >> 1; j > 0; j >>= 1) {
            for (int t = tid; t < (P >> 1); t += 256) {
                int i = ((t & ~(j - 1)) << 1) | (t & (j - 1));
                int l = i | j;
                unsigned ah = skhi[i], al = sklo[i], ch = skhi[l], cl_ = sklo[l];
                bool alt = (ah < ch) || (ah == ch && al < cl_);
                bool agt = (ah > ch) || (ah == ch && al > cl_);
                bool sw = ((i & k) == 0) ? alt : agt;
                if (sw) {
                    skhi[i] = ch; sklo[i] = cl_; skhi[l] = ah; sklo[l] = al;
                    int tp = sperm[i]; sperm[i] = sperm[l]; sperm[l] = tp;
                }
            }
            __syncthreads();
        }
    }
    // phase 2: stage RAW coords in sorted order (256-way parallel gather)
    for (int i = tid; i < n; i += 256) {
        int sl = sperm[i];
        sx1[i] = e_x1[base + sl]; sy1[i] = e_y1[base + sl];
        sx2[i] = e_x2[base + sl]; sy2[i] = e_y2[base + sl];
    }
    __syncthreads();

    // phase 3: wave 0 — registers only; accepted box via sel8 + readlane
    if (tid < 64) {
        int lane = tid;
        float ox1[8], oy1[8], ox2[8], oy2[8], oar[8];
        unsigned alive = 0;
#pragma unroll
        for (int j = 0; j < 8; ++j) {
            int sidx = lane * 8 + j;
            if (sidx < n) {
                float a  = __fadd_rn(sx1[sidx], tb);
                float b_ = __fadd_rn(sy1[sidx], tb);
                float c_ = __fadd_rn(sx2[sidx], tb);
                float d_ = __fadd_rn(sy2[sidx], tb);
                ox1[j] = a; oy1[j] = b_; ox2[j] = c_; oy2[j] = d_;
                oar[j] = __fmul_rn(__fsub_rn(c_, a), __fsub_rn(d_, b_));
                alive |= 1u << j;
            } else {
                ox1[j] = 0.f; oy1[j] = 0.f; ox2[j] = 0.f; oy2[j] = 0.f; oar[j] = 0.f;
            }
        }
        int kout = 0;
        while (kout < NK) {
            unsigned long long bal = __ballot(alive != 0u);
            if (!bal) break;
            int fl = (int)__ffsll(bal) - 1;                           // uniform
            unsigned am = (unsigned)__builtin_amdgcn_readlane((int)alive, fl);
            int js = __ffs(am) - 1;                                   // uniform
            float bx1 = rdlane(sel8(ox1, js), fl);
            float by1 = rdlane(sel8(oy1, js), fl);
            float bx2 = rdlane(sel8(ox2, js), fl);
            float by2 = rdlane(sel8(oy2, js), fl);
            float bar = rdlane(sel8(oar, js), fl);
            if (lane == 0) acc[kout] = fl * 8 + js;   // fire-and-forget
            kout++;
            unsigned kill = 0;
#pragma unroll
            for (int j = 0; j < 8; ++j) {
                float ltx = fmaxf(ox1[j], bx1), lty = fmaxf(oy1[j], by1);
                float rbx = fminf(ox2[j], bx2), rby = fminf(oy2[j], by2);
                float wx = fmaxf(__fsub_rn(rbx, ltx), 0.0f);
                float wy = fmaxf(__fsub_rn(rby, lty), 0.0f);
                float inter = __fmul_rn(wx, wy);
                float den = __fsub_rn(__fadd_rn(oar[j], bar), inter);
                if ((double)inter > C_SUP * (double)den) kill |= 1u << j;
            }
            alive &= ~kill;
        }
        if (lane == 0) { selcnt[g] = kout; s_kout = kout; }
    }
    __syncthreads();

    // phase 4: parallel output write (sorted desc by construction)
    int kc = s_kout;
    for (int k = tid; k < kc; k += 256) {
        int cand = acc[k];
        float* so = selbuf + ((size_t)g * NK + k) * 8;
        so[0] = __uint_as_float(skhi[cand]);
        so[1] = sx1[cand]; so[2] = sy1[cand];
        so[3] = sx2[cand]; so[4] = sy2[cand];
        so[5] = cls; so[6] = (float)(~sklo[cand]); so[7] = 0.0f;
    }
}

// ------ merge: per-image bitonic sort of all accepted, take top-K ----------
__global__ __launch_bounds__(256) void merge_kernel(
    const float* __restrict__ selbuf, const int* __restrict__ selcnt,
    float* __restrict__ out_dets, float* __restrict__ out_kl)
{
    int b = blockIdx.x, tid = threadIdx.x;
    __shared__ unsigned mkhi[MP], mklo[MP], mpay[MP];
    __shared__ int scnt[NCLS], soff[NCLS + 1];

    if (tid < NCLS) scnt[tid] = selcnt[b * NCLS + tid];
    __syncthreads();
    if (tid == 0) {
        int acc = 0;
        for (int c = 0; c < NCLS; ++c) { soff[c] = acc; acc += scnt[c]; }
        soff[NCLS] = acc;
    }
    __syncthreads();
    int tot = soff[NCLS];

    if (tot > MP) {
        // safety fallback: iterative 100-step merge on wave 0
        if (tid >= 64) return;
        int lane = tid;
        int g0 = b * NCLS + lane;
        int g1 = (lane < NCLS - 64) ? g0 + 64 : -1;
        int c0 = scnt[lane];
        int c1 = (g1 >= 0) ? scnt[lane + 64] : 0;
        int p0 = 0, p1 = 0;
        unsigned long long k0c = 0, k1c = 0;
        if (p0 < c0) { const float* h = selbuf + ((size_t)g0 * NK) * 8;
            k0c = ((unsigned long long)__float_as_uint(h[0]) << 32) | (unsigned long long)(~(unsigned)h[6]); }
        if (g1 >= 0 && p1 < c1) { const float* h = selbuf + ((size_t)g1 * NK) * 8;
            k1c = ((unsigned long long)__float_as_uint(h[0]) << 32) | (unsigned long long)(~(unsigned)h[6]); }
        for (int k = 0; k < NK; ++k) {
            bool t1 = (k1c > k0c);
            unsigned long long bk = t1 ? k1c : k0c;
            int bslot = t1 ? (lane + 64) : lane;
            for (int o = 1; o < 64; o <<= 1) {
                unsigned long long k2 = __shfl_xor(bk, o);
                int b2 = __shfl_xor(bslot, o);
                if (k2 > bk) { bk = k2; bslot = b2; }
            }
            if (bk == 0ull) {
                for (int z = k * 5 + lane; z < NK * 5; z += 64)
                    out_dets[(size_t)b * NK * 5 + z] = 0.0f;
                for (int z = k + lane; z < NK; z += 64)
                    out_kl[(size_t)b * NK + z] = -1.0f;
                return;
            }
            int owner = bslot & 63;
            if (lane == owner) {
                bool isA = (bslot < 64);
                int gg = isA ? g0 : g1;
                int pp = isA ? p0 : p1;
                const float* e = selbuf + ((size_t)gg * NK + pp) * 8;
                size_t o = ((size_t)b * NK + k) * 5;
                out_dets[o + 0] = e[1]; out_dets[o + 1] = e[2];
                out_dets[o + 2] = e[3]; out_dets[o + 3] = e[4];
                out_dets[o + 4] = e[0];
                out_kl[(size_t)b * NK + k] = e[5];
                if (isA) {
                    p0++; k0c = 0;
                    if (p0 < c0) { const float* h = selbuf + ((size_t)g0 * NK + p0) * 8;
                        k0c = ((unsigned long long)__float_as_uint(h[0]) << 32) | (unsigned long long)(~(unsigned)h[6]); }
                } else {
                    p1++; k1c = 0;
                    if (p1 < c1) { const float* h = selbuf + ((size_t)g1 * NK + p1) * 8;
                        k1c = ((unsigned long long)__float_as_uint(h[0]) << 32) | (unsigned long long)(~(unsigned)h[6]); }
                }
            }
        }
        return;
    }

    // fast path: load all accepted entries, bitonic sort desc, write top-K
    for (int c = 0; c < NCLS; ++c) {
        int off = soff[c], cnt = scnt[c];
        for (int i = tid; i < cnt; i += 256) {
            const float* e = selbuf + ((size_t)(b * NCLS + c) * NK + i) * 8;
            mkhi[off + i] = __float_as_uint(e[0]);
            mklo[off + i] = ~((unsigned)e[6]);
            mpay[off + i] = (unsigned)(c * 128 + i);
        }
    }
    int P = 256; while (P < tot) P <<= 1;
    for (int i = tot + tid; i < P; i += 256) { mkhi[i] = 0u; mklo[i] = 0u; mpay[i] = 0u; }
    __syncthreads();
    for (int k = 2; k <= P; k <<= 1) {
        for (int j = k >> 1; j > 0; j >>= 1) {
            for (int t = tid; t < (P >> 1); t += 256) {
                int i = ((t & ~(j - 1)) << 1) | (t & (j - 1));
                int l = i | j;
                unsigned ah = mkhi[i], al = mklo[i], ch = mkhi[l], cl_ = mklo[l];
                bool alt = (ah < ch) || (ah == ch && al < cl_);
                bool agt = (ah > ch) || (ah == ch && al > cl_);
                bool sw = ((i & k) == 0) ? alt : agt;
                if (sw) {
                    mkhi[i] = ch; mklo[i] = cl_; mkhi[l] = ah; mklo[l] = al;
                    unsigned tp = mpay[i]; mpay[i] = mpay[l]; mpay[l] = tp;
                }
            }
            __syncthreads();
        }
    }
    int kc = (tot < NK) ? tot : NK;
    for (int k = tid; k < NK; k += 256) {
        size_t o = ((size_t)b * NK + k) * 5;
        if (k < kc) {
            unsigned pay = mpay[k];
            int c = (int)(pay >> 7), p = (int)(pay & 127);
            const float* e = selbuf + ((size_t)(b * NCLS + c) * NK + p) * 8;
            out_dets[o + 0] = e[1]; out_dets[o + 1] = e[2];
            out_dets[o + 2] = e[3]; out_dets[o + 3] = e[4];
            out_dets[o + 4] = e[0];
            out_kl[(size_t)b * NK + k] = e[5];
        } else {
            out_dets[o + 0] = 0.0f; out_dets[o + 1] = 0.0f;
            out_dets[o + 2] = 0.0f; out_dets[o + 3] = 0.0f;
            out_dets[o + 4] = 0.0f;
            out_kl[(size_t)b * NK + k] = -1.0f;
        }
    }
}

extern "C" void kernel_launch(void* const* d_in, const int* in_sizes, int n_in,
                              void* d_out, int out_size, void* d_ws, size_t ws_size,
                              hipStream_t stream) {
    const float* logits = (const float*)d_in[0];
    const float* reg    = (const float*)d_in[1];
    const float* props  = (const float*)d_in[2];
    const float* gtb    = (const float*)d_in[3];
    const int*   gtl    = (const int*)d_in[4];

    float* out          = (float*)d_out;
    float* out_dets     = out;                    // NB*NK*5 = 2000
    float* out_kl       = out + NB * NK * 5;      // NB*NK   = 400
    float* out_assigned = out_kl + NB * NK;       // NB*NN   = 24000
    float* out_matched  = out_assigned + NB * NN; // NB*NN   = 24000

    char* ws = (char*)d_ws;
    int*   cursors = (int*)(ws + 0);              // 360*32*4 = 46080 B
    int*   selcnt  = (int*)(ws + 49152);          // 1440 B
    float* selbuf  = (float*)(ws + 53248);        // 360*100*8*4 = 1152000 B
    size_t off_ent = 1205248;

    long avail = (long)ws_size - (long)off_ent;
    long per_slot = 6L * 4L * NBUC;               // 8640 B per slot index
    long slotsl = (avail > 0) ? avail / per_slot : 0;
    int slots = (int)((slotsl > SLOTS_MAX) ? SLOTS_MAX : (slotsl < 0 ? 0 : slotsl));

    size_t fsz = (size_t)NBUC * slots;            // floats per field
    float* e_sc = (float*)(ws + off_ent);
    float* e_x1 = e_sc + fsz;
    float* e_y1 = e_x1 + fsz;
    float* e_x2 = e_y1 + fsz;
    float* e_y2 = e_x2 + fsz;
    float* e_id = e_y2 + fsz;

    hipMemsetAsync(cursors, 0, NBUC * CUR_STRIDE * sizeof(int), stream);
    const int MATCH_BLOCKS = (NB * NN + 255) / 256;   // 94
    fused_kernel<<<RS_BLOCKS + MATCH_BLOCKS, 256, 0, stream>>>(
        logits, reg, props, gtb, gtl, out_assigned, out_matched,
        cursors, e_sc, e_x1, e_y1, e_x2, e_y2, e_id, slots);
    bucket_nms_kernel<<<NBUC, 256, 0, stream>>>(
        cursors, slots, e_sc, e_x1, e_y1, e_x2, e_y2, e_id, selbuf, selcnt);
    merge_kernel<<<NB, 256, 0, stream>>>(selbuf, selcnt, out_dets, out_kl);
}